// Round 13
// baseline (531.728 us; speedup 1.0000x reference)
//
#include <hip/hip_runtime.h>
#include <hip/hip_bf16.h>

#define N_TOK 32768
#define DIM   256
#define KCB   8192
#define CAP   64
#define MARGIN 1.75e-4f

typedef __attribute__((ext_vector_type(8))) short short8v;   // 8 bf16
typedef __attribute__((ext_vector_type(4))) float f32x4;

__device__ __forceinline__ unsigned int mono_f32(float f) {
    unsigned int u = __float_as_uint(f);
    return (u >> 31) ? ~u : (u | 0x80000000u);
}
__device__ __forceinline__ float invmono_f32(unsigned int m) {
    unsigned int u = (m & 0x80000000u) ? (m & 0x7FFFFFFFu) : ~m;
    return __uint_as_float(u);
}
__device__ __forceinline__ unsigned long long shfl_xor_u64(unsigned long long v, int m) {
    unsigned int lo = (unsigned int)v, hi = (unsigned int)(v >> 32);
    lo = __shfl_xor(lo, m, 64);
    hi = __shfl_xor(hi, m, 64);
    return ((unsigned long long)hi << 32) | lo;
}
__device__ __forceinline__ void gl_lds16(const void* g, void* l) {
    __builtin_amdgcn_global_load_lds(
        (const __attribute__((address_space(1))) unsigned int*)g,
        (__attribute__((address_space(3))) unsigned int*)l, 16, 0, 0);
}
__device__ __forceinline__ unsigned int rne16(float f) {
    unsigned int b = __float_as_uint(f);
    return (b + 0x7FFFu + ((b >> 16) & 1u)) >> 16;
}

// ---------------------------------------------------------------------------
// transpose w_out [D][D] -> wT[j][d]
// ---------------------------------------------------------------------------
__global__ __launch_bounds__(256) void transpose_w(const float* __restrict__ w,
                                                   float* __restrict__ wT) {
    __shared__ float tile[32][33];
    int bx = blockIdx.x & 7, by = blockIdx.x >> 3;
    int x0 = bx * 32, y0 = by * 32;
    int tx = threadIdx.x & 31, ty = threadIdx.x >> 5;
    #pragma unroll
    for (int i = 0; i < 32; i += 8)
        tile[ty + i][tx] = w[(y0 + ty + i) * DIM + x0 + tx];
    __syncthreads();
    #pragma unroll
    for (int i = 0; i < 32; i += 8)
        wT[(x0 + ty + i) * DIM + y0 + tx] = tile[tx][ty + i];
}

// ---------------------------------------------------------------------------
// codebook[k][d] = sum_j emb[k][j]*w_out[d][j], sequential-j FMA chain (BLAS order)
// ---------------------------------------------------------------------------
#define KPB 8
__global__ __launch_bounds__(256) void build_codebook(const float* __restrict__ emb,
                                                      const float* __restrict__ wT,
                                                      float* __restrict__ cb) {
    __shared__ float e[KPB][DIM];
    const int k0 = blockIdx.x * KPB;
    const int t = threadIdx.x;
    for (int i = t; i < KPB * DIM / 4; i += 256)
        ((float4*)&e[0][0])[i] = ((const float4*)(emb + (size_t)k0 * DIM))[i];
    __syncthreads();
    const int d = t;
    float acc[KPB];
    #pragma unroll
    for (int kk = 0; kk < KPB; ++kk) acc[kk] = 0.f;
    for (int j = 0; j < DIM; ++j) {
        float w = wT[j * DIM + d];
        #pragma unroll
        for (int kk = 0; kk < KPB; ++kk)
            acc[kk] = fmaf(e[kk][j], w, acc[kk]);
    }
    #pragma unroll
    for (int kk = 0; kk < KPB; ++kk)
        cb[(size_t)(k0 + kk) * DIM + d] = acc[kk];
}

// ---------------------------------------------------------------------------
// numpy pairwise sum-of-squares (exact np order), 2 threads per row,
// FUSED with fp32->bf16 (RNE) conversion (bfout != null).
// ---------------------------------------------------------------------------
__global__ __launch_bounds__(256) void sumsq_np_bf(const float* __restrict__ a,
                                                   float* __restrict__ out,
                                                   uint4* __restrict__ bfout) {
    #pragma clang fp contract(off)
    int idx = blockIdx.x * 256 + threadIdx.x;
    int r = idx >> 1, h = idx & 1;
    const float* b = a + (size_t)r * DIM + h * 128;
    uint4* dst = bfout ? bfout + ((size_t)r * 32 + h * 16) : (uint4*)0;
    float r0 = 0.f, r1 = 0.f, r2 = 0.f, r3 = 0.f,
          r4 = 0.f, r5 = 0.f, r6 = 0.f, r7 = 0.f;
    #pragma unroll
    for (int i = 0; i < 128; i += 8) {
        float4 p = *(const float4*)(b + i);
        float4 q = *(const float4*)(b + i + 4);
        if (bfout) {
            uint4 u;
            u.x = rne16(p.x) | (rne16(p.y) << 16);
            u.y = rne16(p.z) | (rne16(p.w) << 16);
            u.z = rne16(q.x) | (rne16(q.y) << 16);
            u.w = rne16(q.z) | (rne16(q.w) << 16);
            dst[i >> 3] = u;
        }
        r0 = r0 + p.x * p.x; r1 = r1 + p.y * p.y;
        r2 = r2 + p.z * p.z; r3 = r3 + p.w * p.w;
        r4 = r4 + q.x * q.x; r5 = r5 + q.y * q.y;
        r6 = r6 + q.z * q.z; r7 = r7 + q.w * q.w;
    }
    float half = ((r0 + r1) + (r2 + r3)) + ((r4 + r5) + (r6 + r7));
    float other = __shfl_xor(half, 1, 64);
    if (h == 0) out[r] = half + other;
}

// ---------------------------------------------------------------------------
// Phase 1: bf16 MFMA score GEMM + per-row running max + candidate collection.
// 256x256 tile, 8 waves (4x2 grid, 64x128/wave, acc[4][8]), BK=64.
// Quarter-tile counted pipeline (T3+T4+T5): each K-step = 4 quarters of
// 16 KiB (A-kk0, A-kk1, B-kk0, B-kk1; 64-B rows), ring of 8 slots (128 KiB).
// 4 phases per K-step (kk x n-half); each phase: ds_read subset, issue 1-2
// quarter stages for steps s+1/s+2, s_barrier, setprio(1) 16 MFMA setprio(0).
// Steady-state waits: vmcnt(6) at P0/P1 only (3 quarters in flight), no wait
// at P2/P3; vmcnt(0) only in the final step. Hand-verified load numbering.
// Swizzle for 64-B rows: chunk ^= (row ^ row>>2)&3 (~2% conflict cost, R11).
// ---------------------------------------------------------------------------
__global__ __launch_bounds__(512, 2) void score_collect(
    const unsigned short* __restrict__ xbf,
    const unsigned short* __restrict__ cbbf,
    unsigned int* __restrict__ gmax,
    unsigned int* __restrict__ ccnt,
    unsigned short* __restrict__ cand)
{
    __shared__ unsigned char lds[133120];   // A slots [0,64K), B slots [64K,128K), aux @128K
    float* auxm = (float*)(lds + 131072);   // [2][256]
    const int t = threadIdx.x;
    const int l = t & 63, w = t >> 6;
    const int g = l >> 4, c = l & 15;
    const int wr = w >> 1, wc = w & 1;      // 4x2 wave grid: 64 rows x 128 cols
    const int bid = blockIdx.x;
    const int bx = (bid & 7) + 8 * ((bid >> 3) & 15);   // XCD-bijective decode
    const int by = bid >> 7;
    const int row0 = bx * 256;
    const int col0 = by * 256;

    f32x4 acc[4][8];
    #pragma unroll
    for (int m = 0; m < 4; ++m)
        #pragma unroll
        for (int n = 0; n < 8; ++n) acc[m][n] = (f32x4){0.f, 0.f, 0.f, 0.f};

    const char* xg = (const char*)xbf  + (size_t)row0 * 512;
    const char* cg = (const char*)cbbf + (size_t)col0 * 512;
    short8v af[4], bv[4];
    // read swizzle: row%4 == c%4, (row>>2)%4 == (c>>2)%4 for all fragment rows
    const int swq = ((g ^ (c & 3) ^ ((c >> 2) & 3)) & 3) * 16;

#define ASL(p2_, kkh_) ((p2_) * 32768 + (kkh_) * 16384)
#define BSL(p2_, kkh_) (65536 + (p2_) * 32768 + (kkh_) * 16384)

// stage one 16-KiB quarter: matrix half kkh of K-step s -> slot
#define STG(ptr_, slot_, s_, kkh_)                                             \
    do {                                                                       \
        _Pragma("unroll")                                                      \
        for (int r_ = 0; r_ < 2; ++r_) {                                       \
            int i_ = r_ * 512 + t;                                             \
            int row_ = i_ >> 2, pc_ = i_ & 3;                                  \
            int sz_ = (row_ ^ (row_ >> 2)) & 3;                                \
            gl_lds16((ptr_) + (size_t)row_ * 512 + (s_) * 128 + (kkh_) * 64    \
                             + ((pc_ ^ sz_) * 16),                             \
                     lds + (slot_) + i_ * 16);                                 \
        }                                                                      \
    } while (0)

#define RDA(slot_)                                                             \
    do {                                                                       \
        const unsigned char* ap_ = lds + (slot_);                              \
        _Pragma("unroll")                                                      \
        for (int m = 0; m < 4; ++m)                                            \
            af[m] = *(const short8v*)(ap_ + (64 * wr + 16 * m + c) * 64 + swq);\
    } while (0)

#define RDB(slot_, nh_)                                                        \
    do {                                                                       \
        const unsigned char* bp_ = lds + (slot_);                              \
        _Pragma("unroll")                                                      \
        for (int j = 0; j < 4; ++j)                                            \
            bv[j] = *(const short8v*)(bp_ +                                    \
                (128 * wc + 16 * ((nh_) * 4 + j) + c) * 64 + swq);             \
    } while (0)

#define MM(nh_)                                                                \
    do {                                                                       \
        __builtin_amdgcn_s_setprio(1);                                         \
        _Pragma("unroll")                                                      \
        for (int m = 0; m < 4; ++m)                                            \
            _Pragma("unroll")                                                  \
            for (int j = 0; j < 4; ++j)                                        \
                acc[m][(nh_) * 4 + j] = __builtin_amdgcn_mfma_f32_16x16x32_bf16(\
                    af[m], bv[j], acc[m][(nh_) * 4 + j], 0, 0, 0);             \
        __builtin_amdgcn_s_setprio(0);                                         \
    } while (0)

#define BAR() do { __builtin_amdgcn_s_barrier(); asm volatile("" ::: "memory"); } while (0)
#define WV6() asm volatile("s_waitcnt vmcnt(6)" ::: "memory")
#define WV4() asm volatile("s_waitcnt vmcnt(4)" ::: "memory")
#define WV0() asm volatile("s_waitcnt vmcnt(0)" ::: "memory")

    // ---- prologue: A0(0),B0(0),A1(0),B1(0),A0(1) = 10 loads ----
    STG(xg, ASL(0, 0), 0, 0);
    STG(cg, BSL(0, 0), 0, 0);
    STG(xg, ASL(0, 1), 0, 1);
    STG(cg, BSL(0, 1), 0, 1);
    STG(xg, ASL(1, 0), 1, 0);
    WV6(); BAR();                      // A0(0),B0(0) landed

    // ---- s = 0 (parity 0) ----
    RDA(ASL(0, 0)); RDB(BSL(0, 0), 0);
    STG(cg, BSL(1, 0), 1, 0); STG(xg, ASL(1, 1), 1, 1);
    MM(0);
    WV6(); BAR();                      // B1(0) landed
    RDB(BSL(0, 0), 1);
    STG(cg, BSL(1, 1), 1, 1);
    MM(1);
    BAR();
    RDA(ASL(0, 1)); RDB(BSL(0, 1), 0);
    STG(xg, ASL(0, 0), 2, 0);          // A0(2)
    MM(0);
    BAR();
    RDB(BSL(0, 1), 1);
    MM(1);

    // ---- s = 1 (parity 1) ----
    WV6(); BAR();                      // A0(1),B0(1) landed
    RDA(ASL(1, 0)); RDB(BSL(1, 0), 0);
    STG(cg, BSL(0, 0), 2, 0); STG(xg, ASL(0, 1), 2, 1);
    MM(0);
    WV6(); BAR();                      // B1(1) landed
    RDB(BSL(1, 0), 1);
    STG(cg, BSL(0, 1), 2, 1);
    MM(1);
    BAR();
    RDA(ASL(1, 1)); RDB(BSL(1, 1), 0);
    STG(xg, ASL(1, 0), 3, 0);          // A0(3)
    MM(0);
    BAR();
    RDB(BSL(1, 1), 1);
    MM(1);

    // ---- s = 2 (parity 0) ----
    WV6(); BAR();                      // A0(2),B0(2) landed
    RDA(ASL(0, 0)); RDB(BSL(0, 0), 0);
    STG(cg, BSL(1, 0), 3, 0); STG(xg, ASL(1, 1), 3, 1);
    MM(0);
    WV6(); BAR();                      // B1(2) landed
    RDB(BSL(0, 0), 1);
    STG(cg, BSL(1, 1), 3, 1);
    MM(1);
    BAR();
    RDA(ASL(0, 1)); RDB(BSL(0, 1), 0);
    MM(0);
    BAR();
    RDB(BSL(0, 1), 1);
    MM(1);

    // ---- s = 3 (parity 1, tail) ----
    WV4(); BAR();                      // A0(3),B0(3) landed
    RDA(ASL(1, 0)); RDB(BSL(1, 0), 0);
    MM(0);
    WV0(); BAR();                      // B1(3) landed (all drained)
    RDB(BSL(1, 0), 1);
    MM(1);
    BAR();
    RDA(ASL(1, 1)); RDB(BSL(1, 1), 0);
    MM(0);
    BAR();
    RDB(BSL(1, 1), 1);
    MM(1);

#undef STG
#undef RDA
#undef RDB
#undef MM
#undef BAR
#undef WV6
#undef WV4
#undef WV0
#undef ASL
#undef BSL

    // ---- epilogue: C/D layout col = c, row = 4*g + j within each 16x16 ----
    __syncthreads();
    #pragma unroll
    for (int m = 0; m < 4; ++m)
        #pragma unroll
        for (int j = 0; j < 4; ++j) {
            float v = acc[m][0][j];
            #pragma unroll
            for (int n = 1; n < 8; ++n) v = fmaxf(v, acc[m][n][j]);
            #pragma unroll
            for (int msk = 1; msk < 16; msk <<= 1)
                v = fmaxf(v, __shfl_xor(v, msk, 64));
            if (c == 0) auxm[wc * 256 + 64 * wr + 16 * m + 4 * g + j] = v;
        }
    __syncthreads();

    if (wc == 0 && c == 0) {
        float vm[16];
        unsigned int ou[16];
        #pragma unroll
        for (int i = 0; i < 16; ++i) {
            int row = 64 * wr + 16 * (i >> 2) + 4 * g + (i & 3);
            vm[i] = fmaxf(auxm[row], auxm[256 + row]);
        }
        #pragma unroll
        for (int i = 0; i < 16; ++i) {
            int row = 64 * wr + 16 * (i >> 2) + 4 * g + (i & 3);
            ou[i] = atomicMax(&gmax[row0 + row], mono_f32(vm[i]));
        }
        #pragma unroll
        for (int i = 0; i < 16; ++i) {
            int row = 64 * wr + 16 * (i >> 2) + 4 * g + (i & 3);
            auxm[row] = fmaxf(vm[i], invmono_f32(ou[i]));
        }
    }
    __syncthreads();

    #pragma unroll
    for (int m = 0; m < 4; ++m)
        #pragma unroll
        for (int j = 0; j < 4; ++j) {
            int lrow = 64 * wr + 16 * m + 4 * g + j;
            float thr = auxm[lrow] - MARGIN;
            #pragma unroll
            for (int n = 0; n < 8; ++n) {
                float s = acc[m][n][j];
                if (s >= thr) {
                    int row = row0 + lrow;
                    unsigned int idx = atomicAdd(&ccnt[row], 1u);
                    if (idx < CAP)
                        cand[((size_t)row << 6) + idx] =
                            (unsigned short)(col0 + 128 * wc + 16 * n + c);
                }
            }
        }
}

// ---------------------------------------------------------------------------
// Exact np-chain distance: ascending-k fp32 fmaf chain (BLAS order).
// ---------------------------------------------------------------------------
__device__ __forceinline__ unsigned long long np_dist_pack(
    const float4* __restrict__ xr4, const float* __restrict__ cb,
    int k, float X2, const float* __restrict__ c2)
{
    #pragma clang fp contract(off)
    const float4* cr4 = (const float4*)(cb + (size_t)k * DIM);
    float a = 0.f;
    #pragma unroll 8
    for (int t4 = 0; t4 < DIM / 4; ++t4) {
        float4 xv = xr4[t4];
        float4 cv = cr4[t4];
        a = fmaf(xv.x, cv.x, a);
        a = fmaf(xv.y, cv.y, a);
        a = fmaf(xv.z, cv.z, a);
        a = fmaf(xv.w, cv.w, a);
    }
    float u  = X2 - 2.0f * a;
    float dd = u + c2[k];
    return ((unsigned long long)mono_f32(dd) << 32) | (unsigned int)k;
}

// ---------------------------------------------------------------------------
// Phase 2: exact rescore of candidates. One wave per row, lane = candidate.
// ---------------------------------------------------------------------------
__global__ __launch_bounds__(256) void exact_select(
    const float* __restrict__ x, const float* __restrict__ cb,
    const float* __restrict__ x2, const float* __restrict__ c2,
    const unsigned int* __restrict__ ccnt, const unsigned short* __restrict__ cand,
    unsigned long long* __restrict__ best)
{
    const int l = threadIdx.x & 63;
    const int row = (blockIdx.x * 256 + threadIdx.x) >> 6;
    const unsigned int cnt = ccnt[row];
    const float4* xr4 = (const float4*)(x + (size_t)row * DIM);
    const float X2 = x2[row];
    unsigned long long bp = ~0ull;

    if (cnt <= CAP) {
        if (l < (int)cnt) {
            int k = (int)cand[((size_t)row << 6) + l];
            bp = np_dist_pack(xr4, cb, k, X2, c2);
        }
    } else {
        for (int k = l; k < KCB; k += 64) {
            unsigned long long pk = np_dist_pack(xr4, cb, k, X2, c2);
            if (pk < bp) bp = pk;
        }
    }
    #pragma unroll
    for (int m = 1; m < 64; m <<= 1) {
        unsigned long long v = shfl_xor_u64(bp, m);
        if (v < bp) bp = v;
    }
    if (l == 0) best[row] = bp;
}

// ---------------------------------------------------------------------------
// fp32 fallback score kernel (used only if ws is too small)
// ---------------------------------------------------------------------------
__global__ __launch_bounds__(256, 4) void score_argmin(const float* __restrict__ x,
                                                       const float* __restrict__ cb,
                                                       const float* __restrict__ c2,
                                                       const float* __restrict__ x2,
                                                       unsigned long long* __restrict__ best) {
    #pragma clang fp contract(off)
    __shared__ float As[16][128];
    __shared__ float Bs[16][128];
    const int row0 = blockIdx.x * 128;
    const int col0 = blockIdx.y * 128;
    const int t = threadIdx.x;
    const int tn = t & 15, tm = t >> 4;
    const int lrow = t >> 1, lseg = (t & 1) * 4;
    float acc[8][8];
    #pragma unroll
    for (int i = 0; i < 8; ++i)
        #pragma unroll
        for (int j = 0; j < 8; ++j) acc[i][j] = 0.f;
    const float* xp = x  + (size_t)(row0 + lrow) * DIM + lseg;
    const float* cp = cb + (size_t)(col0 + lrow) * DIM + lseg;
    for (int k0 = 0; k0 < DIM; k0 += 16) {
        float4 a0 = *(const float4*)(xp + k0);
        float4 a1 = *(const float4*)(xp + k0 + 8);
        float4 b0 = *(const float4*)(cp + k0);
        float4 b1 = *(const float4*)(cp + k0 + 8);
        __syncthreads();
        As[lseg + 0][lrow] = a0.x; As[lseg + 1][lrow] = a0.y;
        As[lseg + 2][lrow] = a0.z; As[lseg + 3][lrow] = a0.w;
        As[8 + lseg + 0][lrow] = a1.x; As[8 + lseg + 1][lrow] = a1.y;
        As[8 + lseg + 2][lrow] = a1.z; As[8 + lseg + 3][lrow] = a1.w;
        Bs[lseg + 0][lrow] = b0.x; Bs[lseg + 1][lrow] = b0.y;
        Bs[lseg + 2][lrow] = b0.z; Bs[lseg + 3][lrow] = b0.w;
        Bs[8 + lseg + 0][lrow] = b1.x; Bs[8 + lseg + 1][lrow] = b1.y;
        Bs[8 + lseg + 2][lrow] = b1.z; Bs[8 + lseg + 3][lrow] = b1.w;
        __syncthreads();
        #pragma unroll
        for (int kk = 0; kk < 16; ++kk) {
            float a[8], b[8];
            *(float4*)(a)     = *(const float4*)&As[kk][tm * 4];
            *(float4*)(a + 4) = *(const float4*)&As[kk][64 + tm * 4];
            *(float4*)(b)     = *(const float4*)&Bs[kk][tn * 4];
            *(float4*)(b + 4) = *(const float4*)&Bs[kk][64 + tn * 4];
            #pragma unroll
            for (int i = 0; i < 8; ++i)
                #pragma unroll
                for (int j = 0; j < 8; ++j)
                    acc[i][j] = fmaf(a[i], b[j], acc[i][j]);
        }
    }
    float c2v[8], x2v[8];
    #pragma unroll
    for (int j = 0; j < 4; ++j) {
        c2v[j]     = c2[col0 + tn * 4 + j];
        c2v[4 + j] = c2[col0 + 64 + tn * 4 + j];
    }
    #pragma unroll
    for (int i = 0; i < 4; ++i) {
        x2v[i]     = x2[row0 + tm * 4 + i];
        x2v[4 + i] = x2[row0 + 64 + tm * 4 + i];
    }
    #pragma unroll
    for (int i = 0; i < 8; ++i) {
        unsigned long long bp = ~0ull;
        #pragma unroll
        for (int j = 0; j < 8; ++j) {
            float tt = 2.0f * acc[i][j];
            float u  = x2v[i] - tt;
            float dd = u + c2v[j];
            int id = col0 + ((j < 4) ? (tn * 4 + j) : (64 + tn * 4 + (j - 4)));
            unsigned long long pk = ((unsigned long long)mono_f32(dd) << 32) | (unsigned int)id;
            if (pk < bp) bp = pk;
        }
        #pragma unroll
        for (int m = 1; m < 16; m <<= 1) {
            unsigned long long v = shfl_xor_u64(bp, m);
            if (v < bp) bp = v;
        }
        if (tn == 0) {
            int gr = row0 + ((i < 4) ? (tm * 4 + i) : (64 + tm * 4 + (i - 4)));
            atomicMin(&best[gr], bp);
        }
    }
}

// ---------------------------------------------------------------------------
// finalize: 16 rows per block; gather q, write quantized + ids(float),
// per-block loss partial (no atomics).
// ---------------------------------------------------------------------------
__global__ __launch_bounds__(256) void finalize(const float* __restrict__ x,
                                                const float* __restrict__ cb,
                                                const unsigned long long* __restrict__ best,
                                                float* __restrict__ out,
                                                float* __restrict__ partial) {
    __shared__ float rsum[16];
    const int t = threadIdx.x;
    const int rloc = t >> 4, seg = t & 15;
    const int r = blockIdx.x * 16 + rloc;
    const int id = (int)(best[r] & 0xFFFFFFFFu);
    const float4* xp = (const float4*)(x  + (size_t)r  * DIM) + seg * 4;
    const float4* cp = (const float4*)(cb + (size_t)id * DIM) + seg * 4;
    float4*       op = (float4*)(out + (size_t)r * DIM) + seg * 4;
    float s = 0.f;
    #pragma unroll
    for (int i = 0; i < 4; ++i) {
        float4 xv = xp[i], qv = cp[i];
        op[i] = qv;
        float dx = xv.x - qv.x, dy = xv.y - qv.y;
        float dz = xv.z - qv.z, dw = xv.w - qv.w;
        s += dx * dx + dy * dy + dz * dz + dw * dw;
    }
    #pragma unroll
    for (int m = 1; m < 16; m <<= 1) s += __shfl_xor(s, m, 64);
    if (seg == 0) {
        rsum[rloc] = s;
        out[(size_t)N_TOK * DIM + r] = (float)id;
    }
    __syncthreads();
    if (t == 0) {
        float bs = 0.f;
        #pragma unroll
        for (int i = 0; i < 16; ++i) bs += rsum[i];
        partial[blockIdx.x] = bs;
    }
}

// single block: sum 2048 partials, write loss scalar
__global__ __launch_bounds__(256) void reduce_loss(const float* __restrict__ partial,
                                                   float* __restrict__ out) {
    float s = 0.f;
    for (int i = threadIdx.x; i < 2048 / 4; i += 256) {
        float4 v = ((const float4*)partial)[i];
        s += (v.x + v.y) + (v.z + v.w);
    }
    #pragma unroll
    for (int o = 32; o > 0; o >>= 1) s += __shfl_down(s, o, 64);
    __shared__ float w4[4];
    if ((threadIdx.x & 63) == 0) w4[threadIdx.x >> 6] = s;
    __syncthreads();
    if (threadIdx.x == 0)
        out[(size_t)N_TOK * DIM + N_TOK] =
            (w4[0] + w4[1] + w4[2] + w4[3]) * (1.25f / ((float)N_TOK * (float)DIM));
}

// ---------------------------------------------------------------------------
extern "C" void kernel_launch(void* const* d_in, const int* in_sizes, int n_in,
                              void* d_out, int out_size, void* d_ws, size_t ws_size,
                              hipStream_t stream) {
    const float* x     = (const float*)d_in[0];
    const float* emb   = (const float*)d_in[1];
    const float* w_out = (const float*)d_in[2];
    float* out = (float*)d_out;

    char* ws = (char*)d_ws;
    unsigned long long* best = (unsigned long long*)ws;              //        0 (256 KiB)
    float* x2 = (float*)(ws + 262400);                               //   262400
    float* wT = (float*)(ws + 393472);                               //   393472 (reused as loss partial)
    float* cb = (float*)(ws + 655616);                               //   655616 (8 MiB)
    float* c2 = (float*)(ws + 9044224);                              //  9044224
    unsigned int*   gmax = (unsigned int*)(ws + 9076992);            //  9076992 (128 KiB)
    unsigned int*   ccnt = (unsigned int*)(ws + 9208064);            //  9208064 (128 KiB)
    unsigned short* cand = (unsigned short*)(ws + 9339136);          //  9339136 (4 MiB)
    unsigned short* xbf  = (unsigned short*)(ws + 13533440);         // 13533440 (16 MiB)
    unsigned short* cbbf = (unsigned short*)(ws + 30310656);         // 30310656 (4 MiB)
    float* partial = wT;                                             // 8 KiB, reuse
    const size_t NEED = 34504960;
    const bool useMfma = (ws_size >= NEED);

    transpose_w   <<<64,  256, 0, stream>>>(w_out, wT);
    build_codebook<<<KCB / KPB, 256, 0, stream>>>(emb, wT, cb);
    sumsq_np_bf   <<<N_TOK * 2 / 256, 256, 0, stream>>>(x, x2,
                      useMfma ? (uint4*)xbf : (uint4*)0);
    sumsq_np_bf   <<<KCB * 2 / 256, 256, 0, stream>>>(cb, c2,
                      useMfma ? (uint4*)cbbf : (uint4*)0);

    if (useMfma) {
        hipMemsetAsync(gmax, 0, 262144, stream);   // gmax + ccnt contiguous
        score_collect <<<4096, 512, 0, stream>>>(xbf, cbbf, gmax, ccnt, cand);
        exact_select  <<<N_TOK / 4, 256, 0, stream>>>(x, cb, x2, c2, ccnt, cand, best);
    } else {
        hipMemsetAsync(best, 0xFF, 262144, stream);
        score_argmin  <<<dim3(N_TOK / 128, KCB / 128), 256, 0, stream>>>(x, cb, c2, x2, best);
    }

    finalize      <<<N_TOK / 16, 256, 0, stream>>>(x, cb, best, out, partial);
    reduce_loss   <<<1, 256, 0, stream>>>(partial, out);
}

// Round 14
// 471.306 us; speedup vs baseline: 1.1282x; 1.1282x over previous
//
#include <hip/hip_runtime.h>
#include <hip/hip_bf16.h>

#define N_TOK 32768
#define DIM   256
#define KCB   8192
#define CAP   64
#define MARGIN 1.75e-4f

typedef __attribute__((ext_vector_type(8))) short short8v;   // 8 bf16
typedef __attribute__((ext_vector_type(4))) float f32x4;

__device__ __forceinline__ unsigned int mono_f32(float f) {
    unsigned int u = __float_as_uint(f);
    return (u >> 31) ? ~u : (u | 0x80000000u);
}
__device__ __forceinline__ float invmono_f32(unsigned int m) {
    unsigned int u = (m & 0x80000000u) ? (m & 0x7FFFFFFFu) : ~m;
    return __uint_as_float(u);
}
__device__ __forceinline__ unsigned long long shfl_xor_u64(unsigned long long v, int m) {
    unsigned int lo = (unsigned int)v, hi = (unsigned int)(v >> 32);
    lo = __shfl_xor(lo, m, 64);
    hi = __shfl_xor(hi, m, 64);
    return ((unsigned long long)hi << 32) | lo;
}
__device__ __forceinline__ void gl_lds16(const void* g, void* l) {
    __builtin_amdgcn_global_load_lds(
        (const __attribute__((address_space(1))) unsigned int*)g,
        (__attribute__((address_space(3))) unsigned int*)l, 16, 0, 0);
}
__device__ __forceinline__ unsigned int rne16(float f) {
    unsigned int b = __float_as_uint(f);
    return (b + 0x7FFFu + ((b >> 16) & 1u)) >> 16;
}

// ---------------------------------------------------------------------------
// transpose w_out [D][D] -> wT[j][d]
// ---------------------------------------------------------------------------
__global__ __launch_bounds__(256) void transpose_w(const float* __restrict__ w,
                                                   float* __restrict__ wT) {
    __shared__ float tile[32][33];
    int bx = blockIdx.x & 7, by = blockIdx.x >> 3;
    int x0 = bx * 32, y0 = by * 32;
    int tx = threadIdx.x & 31, ty = threadIdx.x >> 5;
    #pragma unroll
    for (int i = 0; i < 32; i += 8)
        tile[ty + i][tx] = w[(y0 + ty + i) * DIM + x0 + tx];
    __syncthreads();
    #pragma unroll
    for (int i = 0; i < 32; i += 8)
        wT[(x0 + ty + i) * DIM + y0 + tx] = tile[tx][ty + i];
}

// ---------------------------------------------------------------------------
// codebook[k][d] = sum_j emb[k][j]*w_out[d][j], sequential-j FMA chain (BLAS order)
// ---------------------------------------------------------------------------
#define KPB 8
__global__ __launch_bounds__(256) void build_codebook(const float* __restrict__ emb,
                                                      const float* __restrict__ wT,
                                                      float* __restrict__ cb) {
    __shared__ float e[KPB][DIM];
    const int k0 = blockIdx.x * KPB;
    const int t = threadIdx.x;
    for (int i = t; i < KPB * DIM / 4; i += 256)
        ((float4*)&e[0][0])[i] = ((const float4*)(emb + (size_t)k0 * DIM))[i];
    __syncthreads();
    const int d = t;
    float acc[KPB];
    #pragma unroll
    for (int kk = 0; kk < KPB; ++kk) acc[kk] = 0.f;
    for (int j = 0; j < DIM; ++j) {
        float w = wT[j * DIM + d];
        #pragma unroll
        for (int kk = 0; kk < KPB; ++kk)
            acc[kk] = fmaf(e[kk][j], w, acc[kk]);
    }
    #pragma unroll
    for (int kk = 0; kk < KPB; ++kk)
        cb[(size_t)(k0 + kk) * DIM + d] = acc[kk];
}

// ---------------------------------------------------------------------------
// numpy pairwise sum-of-squares (exact np order), 2 threads per row,
// FUSED with fp32->bf16 (RNE) conversion (bfout != null).
// ---------------------------------------------------------------------------
__global__ __launch_bounds__(256) void sumsq_np_bf(const float* __restrict__ a,
                                                   float* __restrict__ out,
                                                   uint4* __restrict__ bfout) {
    #pragma clang fp contract(off)
    int idx = blockIdx.x * 256 + threadIdx.x;
    int r = idx >> 1, h = idx & 1;
    const float* b = a + (size_t)r * DIM + h * 128;
    uint4* dst = bfout ? bfout + ((size_t)r * 32 + h * 16) : (uint4*)0;
    float r0 = 0.f, r1 = 0.f, r2 = 0.f, r3 = 0.f,
          r4 = 0.f, r5 = 0.f, r6 = 0.f, r7 = 0.f;
    #pragma unroll
    for (int i = 0; i < 128; i += 8) {
        float4 p = *(const float4*)(b + i);
        float4 q = *(const float4*)(b + i + 4);
        if (bfout) {
            uint4 u;
            u.x = rne16(p.x) | (rne16(p.y) << 16);
            u.y = rne16(p.z) | (rne16(p.w) << 16);
            u.z = rne16(q.x) | (rne16(q.y) << 16);
            u.w = rne16(q.z) | (rne16(q.w) << 16);
            dst[i >> 3] = u;
        }
        r0 = r0 + p.x * p.x; r1 = r1 + p.y * p.y;
        r2 = r2 + p.z * p.z; r3 = r3 + p.w * p.w;
        r4 = r4 + q.x * q.x; r5 = r5 + q.y * q.y;
        r6 = r6 + q.z * q.z; r7 = r7 + q.w * q.w;
    }
    float half = ((r0 + r1) + (r2 + r3)) + ((r4 + r5) + (r6 + r7));
    float other = __shfl_xor(half, 1, 64);
    if (h == 0) out[r] = half + other;
}

// ---------------------------------------------------------------------------
// Phase 1: bf16 MFMA score GEMM + per-row running max + candidate collection.
// OCCUPANCY-FIRST config: 256x256 tile, 16 waves (1024 thr) in 4x4 grid,
// 64x64 per wave -> acc[4][4] = 64 AGPRs, ~120 regs/wave -> 16 waves/CU
// (2x the 8-wave cap every previous round was pinned at).
// BK=32, double-buffered (2 x 32 KiB) + 1-deep prefetch (R6-proven loop).
// Swizzle for 64-B rows: physical chunk = logical ^ ((row>>1)&3); fragment
// b128 reads verified balanced: 8 lanes per 4-bank class = conflict-free.
// Epilogue: wave-local 64-col max -> auxm[4][256] -> threads 0-255 merge ->
// ONE atomicMax/row -> threshold append.
// ---------------------------------------------------------------------------
__global__ __launch_bounds__(1024, 4) void score_collect(
    const unsigned short* __restrict__ xbf,
    const unsigned short* __restrict__ cbbf,
    unsigned int* __restrict__ gmax,
    unsigned int* __restrict__ ccnt,
    unsigned short* __restrict__ cand)
{
    __shared__ unsigned char lds[69632];    // buf0 @0, buf1 @32K (A 16K + B 16K), aux @64K
    float* auxm = (float*)(lds + 65536);    // [4][256]
    const int t = threadIdx.x;
    const int l = t & 63, w = t >> 6;       // 16 waves
    const int g = l >> 4, c = l & 15;
    const int wr = w >> 2, wc = w & 3;      // 4x4 wave grid: 64 rows x 64 cols
    const int bid = blockIdx.x;
    const int bx = (bid & 7) + 8 * ((bid >> 3) & 15);   // XCD-bijective decode
    const int by = bid >> 7;
    const int row0 = bx * 256;
    const int col0 = by * 256;

    f32x4 acc[4][4];
    #pragma unroll
    for (int m = 0; m < 4; ++m)
        #pragma unroll
        for (int n = 0; n < 4; ++n) acc[m][n] = (f32x4){0.f, 0.f, 0.f, 0.f};

    const char* xg = (const char*)xbf  + (size_t)row0 * 512;
    const char* cg = (const char*)cbbf + (size_t)col0 * 512;

    // stage s covers k-bytes [s*32*2, +64) of each row; 2 gl_lds16 per thread
#define STAGE(buf, ks)                                                         \
    do {                                                                       \
        const int kb_ = (ks) * 64;                                             \
        unsigned char* la_ = lds + (buf) * 32768;                              \
        {   /* A: 256 rows x 4 chunks = 1024 = one per thread */               \
            int row_ = t >> 2, pc_ = t & 3;                                    \
            int sz_ = (row_ >> 1) & 3;                                         \
            gl_lds16(xg + (size_t)row_ * 512 + kb_ + ((pc_ ^ sz_) * 16),       \
                     la_ + t * 16);                                            \
        }                                                                      \
        {   /* B: 256 cols x 4 chunks */                                       \
            int row_ = t >> 2, pc_ = t & 3;                                    \
            int sz_ = (row_ >> 1) & 3;                                         \
            gl_lds16(cg + (size_t)row_ * 512 + kb_ + ((pc_ ^ sz_) * 16),       \
                     la_ + 16384 + t * 16);                                    \
        }                                                                      \
    } while (0)

#define COMPUTE(buf)                                                           \
    do {                                                                       \
        const unsigned char* la_ = lds + (buf) * 32768;                        \
        const unsigned char* lb_ = la_ + 16384;                                \
        const int swq_ = (g ^ ((c >> 1) & 3)) * 16;                            \
        short8v af[4], bv[4];                                                  \
        _Pragma("unroll")                                                      \
        for (int m = 0; m < 4; ++m)                                            \
            af[m] = *(const short8v*)(la_ + (64 * wr + 16 * m + c) * 64 + swq_); \
        _Pragma("unroll")                                                      \
        for (int n = 0; n < 4; ++n)                                            \
            bv[n] = *(const short8v*)(lb_ + (64 * wc + 16 * n + c) * 64 + swq_); \
        _Pragma("unroll")                                                      \
        for (int m = 0; m < 4; ++m)                                            \
            _Pragma("unroll")                                                  \
            for (int n = 0; n < 4; ++n)                                        \
                acc[m][n] = __builtin_amdgcn_mfma_f32_16x16x32_bf16(           \
                    af[m], bv[n], acc[m][n], 0, 0, 0);                         \
    } while (0)

    STAGE(0, 0);
    asm volatile("s_waitcnt vmcnt(0)" ::: "memory");
    __syncthreads();

    #pragma unroll
    for (int s = 0; s < 8; ++s) {
        if (s < 7) STAGE((s + 1) & 1, s + 1);          // prefetch next K-step
        COMPUTE(s & 1);
        asm volatile("s_waitcnt vmcnt(0)" ::: "memory");
        __syncthreads();
    }
#undef STAGE
#undef COMPUTE

    // ---- epilogue: C/D layout col = c, row = 4*g + j within each 16x16 ----
    // 1) wave-local 64-col max per row -> auxm[wc][row]
    #pragma unroll
    for (int m = 0; m < 4; ++m)
        #pragma unroll
        for (int j = 0; j < 4; ++j) {
            float v = acc[m][0][j];
            #pragma unroll
            for (int n = 1; n < 4; ++n) v = fmaxf(v, acc[m][n][j]);
            #pragma unroll
            for (int msk = 1; msk < 16; msk <<= 1)
                v = fmaxf(v, __shfl_xor(v, msk, 64));
            if (c == 0) auxm[wc * 256 + 64 * wr + 16 * m + 4 * g + j] = v;
        }
    __syncthreads();

    // 2) threads 0-255: merge 4 col-wave maxes, ONE atomicMax per row
    if (t < 256) {
        float vm = fmaxf(fmaxf(auxm[t], auxm[256 + t]),
                         fmaxf(auxm[512 + t], auxm[768 + t]));
        unsigned int ou = atomicMax(&gmax[row0 + t], mono_f32(vm));
        auxm[t] = fmaxf(vm, invmono_f32(ou));          // running global max
    }
    __syncthreads();

    // 3) all waves: threshold = running global max - margin; append candidates
    #pragma unroll
    for (int m = 0; m < 4; ++m)
        #pragma unroll
        for (int j = 0; j < 4; ++j) {
            int lrow = 64 * wr + 16 * m + 4 * g + j;
            float thr = auxm[lrow] - MARGIN;
            #pragma unroll
            for (int n = 0; n < 4; ++n) {
                float s = acc[m][n][j];
                if (s >= thr) {
                    int row = row0 + lrow;
                    unsigned int idx = atomicAdd(&ccnt[row], 1u);
                    if (idx < CAP)
                        cand[((size_t)row << 6) + idx] =
                            (unsigned short)(col0 + 64 * wc + 16 * n + c);
                }
            }
        }
}

// ---------------------------------------------------------------------------
// Exact np-chain distance: ascending-k fp32 fmaf chain (BLAS order).
// ---------------------------------------------------------------------------
__device__ __forceinline__ unsigned long long np_dist_pack(
    const float4* __restrict__ xr4, const float* __restrict__ cb,
    int k, float X2, const float* __restrict__ c2)
{
    #pragma clang fp contract(off)
    const float4* cr4 = (const float4*)(cb + (size_t)k * DIM);
    float a = 0.f;
    #pragma unroll 8
    for (int t4 = 0; t4 < DIM / 4; ++t4) {
        float4 xv = xr4[t4];
        float4 cv = cr4[t4];
        a = fmaf(xv.x, cv.x, a);
        a = fmaf(xv.y, cv.y, a);
        a = fmaf(xv.z, cv.z, a);
        a = fmaf(xv.w, cv.w, a);
    }
    float u  = X2 - 2.0f * a;
    float dd = u + c2[k];
    return ((unsigned long long)mono_f32(dd) << 32) | (unsigned int)k;
}

// ---------------------------------------------------------------------------
// Phase 2: exact rescore of candidates. One wave per row, lane = candidate.
// ---------------------------------------------------------------------------
__global__ __launch_bounds__(256) void exact_select(
    const float* __restrict__ x, const float* __restrict__ cb,
    const float* __restrict__ x2, const float* __restrict__ c2,
    const unsigned int* __restrict__ ccnt, const unsigned short* __restrict__ cand,
    unsigned long long* __restrict__ best)
{
    const int l = threadIdx.x & 63;
    const int row = (blockIdx.x * 256 + threadIdx.x) >> 6;
    const unsigned int cnt = ccnt[row];
    const float4* xr4 = (const float4*)(x + (size_t)row * DIM);
    const float X2 = x2[row];
    unsigned long long bp = ~0ull;

    if (cnt <= CAP) {
        if (l < (int)cnt) {
            int k = (int)cand[((size_t)row << 6) + l];
            bp = np_dist_pack(xr4, cb, k, X2, c2);
        }
    } else {
        for (int k = l; k < KCB; k += 64) {
            unsigned long long pk = np_dist_pack(xr4, cb, k, X2, c2);
            if (pk < bp) bp = pk;
        }
    }
    #pragma unroll
    for (int m = 1; m < 64; m <<= 1) {
        unsigned long long v = shfl_xor_u64(bp, m);
        if (v < bp) bp = v;
    }
    if (l == 0) best[row] = bp;
}

// ---------------------------------------------------------------------------
// fp32 fallback score kernel (used only if ws is too small)
// ---------------------------------------------------------------------------
__global__ __launch_bounds__(256, 4) void score_argmin(const float* __restrict__ x,
                                                       const float* __restrict__ cb,
                                                       const float* __restrict__ c2,
                                                       const float* __restrict__ x2,
                                                       unsigned long long* __restrict__ best) {
    #pragma clang fp contract(off)
    __shared__ float As[16][128];
    __shared__ float Bs[16][128];
    const int row0 = blockIdx.x * 128;
    const int col0 = blockIdx.y * 128;
    const int t = threadIdx.x;
    const int tn = t & 15, tm = t >> 4;
    const int lrow = t >> 1, lseg = (t & 1) * 4;
    float acc[8][8];
    #pragma unroll
    for (int i = 0; i < 8; ++i)
        #pragma unroll
        for (int j = 0; j < 8; ++j) acc[i][j] = 0.f;
    const float* xp = x  + (size_t)(row0 + lrow) * DIM + lseg;
    const float* cp = cb + (size_t)(col0 + lrow) * DIM + lseg;
    for (int k0 = 0; k0 < DIM; k0 += 16) {
        float4 a0 = *(const float4*)(xp + k0);
        float4 a1 = *(const float4*)(xp + k0 + 8);
        float4 b0 = *(const float4*)(cp + k0);
        float4 b1 = *(const float4*)(cp + k0 + 8);
        __syncthreads();
        As[lseg + 0][lrow] = a0.x; As[lseg + 1][lrow] = a0.y;
        As[lseg + 2][lrow] = a0.z; As[lseg + 3][lrow] = a0.w;
        As[8 + lseg + 0][lrow] = a1.x; As[8 + lseg + 1][lrow] = a1.y;
        As[8 + lseg + 2][lrow] = a1.z; As[8 + lseg + 3][lrow] = a1.w;
        Bs[lseg + 0][lrow] = b0.x; Bs[lseg + 1][lrow] = b0.y;
        Bs[lseg + 2][lrow] = b0.z; Bs[lseg + 3][lrow] = b0.w;
        Bs[8 + lseg + 0][lrow] = b1.x; Bs[8 + lseg + 1][lrow] = b1.y;
        Bs[8 + lseg + 2][lrow] = b1.z; Bs[8 + lseg + 3][lrow] = b1.w;
        __syncthreads();
        #pragma unroll
        for (int kk = 0; kk < 16; ++kk) {
            float a[8], b[8];
            *(float4*)(a)     = *(const float4*)&As[kk][tm * 4];
            *(float4*)(a + 4) = *(const float4*)&As[kk][64 + tm * 4];
            *(float4*)(b)     = *(const float4*)&Bs[kk][tn * 4];
            *(float4*)(b + 4) = *(const float4*)&Bs[kk][64 + tn * 4];
            #pragma unroll
            for (int i = 0; i < 8; ++i)
                #pragma unroll
                for (int j = 0; j < 8; ++j)
                    acc[i][j] = fmaf(a[i], b[j], acc[i][j]);
        }
    }
    float c2v[8], x2v[8];
    #pragma unroll
    for (int j = 0; j < 4; ++j) {
        c2v[j]     = c2[col0 + tn * 4 + j];
        c2v[4 + j] = c2[col0 + 64 + tn * 4 + j];
    }
    #pragma unroll
    for (int i = 0; i < 4; ++i) {
        x2v[i]     = x2[row0 + tm * 4 + i];
        x2v[4 + i] = x2[row0 + 64 + tm * 4 + i];
    }
    #pragma unroll
    for (int i = 0; i < 8; ++i) {
        unsigned long long bp = ~0ull;
        #pragma unroll
        for (int j = 0; j < 8; ++j) {
            float tt = 2.0f * acc[i][j];
            float u  = x2v[i] - tt;
            float dd = u + c2v[j];
            int id = col0 + ((j < 4) ? (tn * 4 + j) : (64 + tn * 4 + (j - 4)));
            unsigned long long pk = ((unsigned long long)mono_f32(dd) << 32) | (unsigned int)id;
            if (pk < bp) bp = pk;
        }
        #pragma unroll
        for (int m = 1; m < 16; m <<= 1) {
            unsigned long long v = shfl_xor_u64(bp, m);
            if (v < bp) bp = v;
        }
        if (tn == 0) {
            int gr = row0 + ((i < 4) ? (tm * 4 + i) : (64 + tm * 4 + (i - 4)));
            atomicMin(&best[gr], bp);
        }
    }
}

// ---------------------------------------------------------------------------
// finalize: 16 rows per block; gather q, write quantized + ids(float),
// per-block loss partial (no atomics).
// ---------------------------------------------------------------------------
__global__ __launch_bounds__(256) void finalize(const float* __restrict__ x,
                                                const float* __restrict__ cb,
                                                const unsigned long long* __restrict__ best,
                                                float* __restrict__ out,
                                                float* __restrict__ partial) {
    __shared__ float rsum[16];
    const int t = threadIdx.x;
    const int rloc = t >> 4, seg = t & 15;
    const int r = blockIdx.x * 16 + rloc;
    const int id = (int)(best[r] & 0xFFFFFFFFu);
    const float4* xp = (const float4*)(x  + (size_t)r  * DIM) + seg * 4;
    const float4* cp = (const float4*)(cb + (size_t)id * DIM) + seg * 4;
    float4*       op = (float4*)(out + (size_t)r * DIM) + seg * 4;
    float s = 0.f;
    #pragma unroll
    for (int i = 0; i < 4; ++i) {
        float4 xv = xp[i], qv = cp[i];
        op[i] = qv;
        float dx = xv.x - qv.x, dy = xv.y - qv.y;
        float dz = xv.z - qv.z, dw = xv.w - qv.w;
        s += dx * dx + dy * dy + dz * dz + dw * dw;
    }
    #pragma unroll
    for (int m = 1; m < 16; m <<= 1) s += __shfl_xor(s, m, 64);
    if (seg == 0) {
        rsum[rloc] = s;
        out[(size_t)N_TOK * DIM + r] = (float)id;
    }
    __syncthreads();
    if (t == 0) {
        float bs = 0.f;
        #pragma unroll
        for (int i = 0; i < 16; ++i) bs += rsum[i];
        partial[blockIdx.x] = bs;
    }
}

// single block: sum 2048 partials, write loss scalar
__global__ __launch_bounds__(256) void reduce_loss(const float* __restrict__ partial,
                                                   float* __restrict__ out) {
    float s = 0.f;
    for (int i = threadIdx.x; i < 2048 / 4; i += 256) {
        float4 v = ((const float4*)partial)[i];
        s += (v.x + v.y) + (v.z + v.w);
    }
    #pragma unroll
    for (int o = 32; o > 0; o >>= 1) s += __shfl_down(s, o, 64);
    __shared__ float w4[4];
    if ((threadIdx.x & 63) == 0) w4[threadIdx.x >> 6] = s;
    __syncthreads();
    if (threadIdx.x == 0)
        out[(size_t)N_TOK * DIM + N_TOK] =
            (w4[0] + w4[1] + w4[2] + w4[3]) * (1.25f / ((float)N_TOK * (float)DIM));
}

// ---------------------------------------------------------------------------
extern "C" void kernel_launch(void* const* d_in, const int* in_sizes, int n_in,
                              void* d_out, int out_size, void* d_ws, size_t ws_size,
                              hipStream_t stream) {
    const float* x     = (const float*)d_in[0];
    const float* emb   = (const float*)d_in[1];
    const float* w_out = (const float*)d_in[2];
    float* out = (float*)d_out;

    char* ws = (char*)d_ws;
    unsigned long long* best = (unsigned long long*)ws;              //        0 (256 KiB)
    float* x2 = (float*)(ws + 262400);                               //   262400
    float* wT = (float*)(ws + 393472);                               //   393472 (reused as loss partial)
    float* cb = (float*)(ws + 655616);                               //   655616 (8 MiB)
    float* c2 = (float*)(ws + 9044224);                              //  9044224
    unsigned int*   gmax = (unsigned int*)(ws + 9076992);            //  9076992 (128 KiB)
    unsigned int*   ccnt = (unsigned int*)(ws + 9208064);            //  9208064 (128 KiB)
    unsigned short* cand = (unsigned short*)(ws + 9339136);          //  9339136 (4 MiB)
    unsigned short* xbf  = (unsigned short*)(ws + 13533440);         // 13533440 (16 MiB)
    unsigned short* cbbf = (unsigned short*)(ws + 30310656);         // 30310656 (4 MiB)
    float* partial = wT;                                             // 8 KiB, reuse
    const size_t NEED = 34504960;
    const bool useMfma = (ws_size >= NEED);

    transpose_w   <<<64,  256, 0, stream>>>(w_out, wT);
    build_codebook<<<KCB / KPB, 256, 0, stream>>>(emb, wT, cb);
    sumsq_np_bf   <<<N_TOK * 2 / 256, 256, 0, stream>>>(x, x2,
                      useMfma ? (uint4*)xbf : (uint4*)0);
    sumsq_np_bf   <<<KCB * 2 / 256, 256, 0, stream>>>(cb, c2,
                      useMfma ? (uint4*)cbbf : (uint4*)0);

    if (useMfma) {
        hipMemsetAsync(gmax, 0, 262144, stream);   // gmax + ccnt contiguous
        score_collect <<<4096, 1024, 0, stream>>>(xbf, cbbf, gmax, ccnt, cand);
        exact_select  <<<N_TOK / 4, 256, 0, stream>>>(x, cb, x2, c2, ccnt, cand, best);
    } else {
        hipMemsetAsync(best, 0xFF, 262144, stream);
        score_argmin  <<<dim3(N_TOK / 128, KCB / 128), 256, 0, stream>>>(x, cb, c2, x2, best);
    }

    finalize      <<<N_TOK / 16, 256, 0, stream>>>(x, cb, best, out, partial);
    reduce_loss   <<<1, 256, 0, stream>>>(partial, out);
}

// Round 15
// 463.529 us; speedup vs baseline: 1.1471x; 1.0168x over previous
//
#include <hip/hip_runtime.h>
#include <hip/hip_bf16.h>

#define N_TOK 32768
#define DIM   256
#define KCB   8192
#define CAP   64
#define MARGIN 1.75e-4f

typedef __attribute__((ext_vector_type(8))) short short8v;   // 8 bf16
typedef __attribute__((ext_vector_type(4))) float f32x4;

__device__ __forceinline__ unsigned int mono_f32(float f) {
    unsigned int u = __float_as_uint(f);
    return (u >> 31) ? ~u : (u | 0x80000000u);
}
__device__ __forceinline__ float invmono_f32(unsigned int m) {
    unsigned int u = (m & 0x80000000u) ? (m & 0x7FFFFFFFu) : ~m;
    return __uint_as_float(u);
}
__device__ __forceinline__ unsigned long long shfl_xor_u64(unsigned long long v, int m) {
    unsigned int lo = (unsigned int)v, hi = (unsigned int)(v >> 32);
    lo = __shfl_xor(lo, m, 64);
    hi = __shfl_xor(hi, m, 64);
    return ((unsigned long long)hi << 32) | lo;
}
__device__ __forceinline__ void gl_lds16(const void* g, void* l) {
    __builtin_amdgcn_global_load_lds(
        (const __attribute__((address_space(1))) unsigned int*)g,
        (__attribute__((address_space(3))) unsigned int*)l, 16, 0, 0);
}
__device__ __forceinline__ unsigned int rne16(float f) {
    unsigned int b = __float_as_uint(f);
    return (b + 0x7FFFu + ((b >> 16) & 1u)) >> 16;
}

// ---------------------------------------------------------------------------
// transpose w_out [D][D] -> wT[j][d]
// ---------------------------------------------------------------------------
__global__ __launch_bounds__(256) void transpose_w(const float* __restrict__ w,
                                                   float* __restrict__ wT) {
    __shared__ float tile[32][33];
    int bx = blockIdx.x & 7, by = blockIdx.x >> 3;
    int x0 = bx * 32, y0 = by * 32;
    int tx = threadIdx.x & 31, ty = threadIdx.x >> 5;
    #pragma unroll
    for (int i = 0; i < 32; i += 8)
        tile[ty + i][tx] = w[(y0 + ty + i) * DIM + x0 + tx];
    __syncthreads();
    #pragma unroll
    for (int i = 0; i < 32; i += 8)
        wT[(x0 + ty + i) * DIM + y0 + tx] = tile[tx][ty + i];
}

// ---------------------------------------------------------------------------
// codebook[k][d] = sum_j emb[k][j]*w_out[d][j], sequential-j FMA chain (BLAS order)
// ---------------------------------------------------------------------------
#define KPB 8
__global__ __launch_bounds__(256) void build_codebook(const float* __restrict__ emb,
                                                      const float* __restrict__ wT,
                                                      float* __restrict__ cb) {
    __shared__ float e[KPB][DIM];
    const int k0 = blockIdx.x * KPB;
    const int t = threadIdx.x;
    for (int i = t; i < KPB * DIM / 4; i += 256)
        ((float4*)&e[0][0])[i] = ((const float4*)(emb + (size_t)k0 * DIM))[i];
    __syncthreads();
    const int d = t;
    float acc[KPB];
    #pragma unroll
    for (int kk = 0; kk < KPB; ++kk) acc[kk] = 0.f;
    for (int j = 0; j < DIM; ++j) {
        float w = wT[j * DIM + d];
        #pragma unroll
        for (int kk = 0; kk < KPB; ++kk)
            acc[kk] = fmaf(e[kk][j], w, acc[kk]);
    }
    #pragma unroll
    for (int kk = 0; kk < KPB; ++kk)
        cb[(size_t)(k0 + kk) * DIM + d] = acc[kk];
}

// ---------------------------------------------------------------------------
// numpy pairwise sum-of-squares (exact np order), 2 threads per row,
// FUSED with fp32->bf16 (RNE) conversion (bfout != null).
// ---------------------------------------------------------------------------
__global__ __launch_bounds__(256) void sumsq_np_bf(const float* __restrict__ a,
                                                   float* __restrict__ out,
                                                   uint4* __restrict__ bfout) {
    #pragma clang fp contract(off)
    int idx = blockIdx.x * 256 + threadIdx.x;
    int r = idx >> 1, h = idx & 1;
    const float* b = a + (size_t)r * DIM + h * 128;
    uint4* dst = bfout ? bfout + ((size_t)r * 32 + h * 16) : (uint4*)0;
    float r0 = 0.f, r1 = 0.f, r2 = 0.f, r3 = 0.f,
          r4 = 0.f, r5 = 0.f, r6 = 0.f, r7 = 0.f;
    #pragma unroll
    for (int i = 0; i < 128; i += 8) {
        float4 p = *(const float4*)(b + i);
        float4 q = *(const float4*)(b + i + 4);
        if (bfout) {
            uint4 u;
            u.x = rne16(p.x) | (rne16(p.y) << 16);
            u.y = rne16(p.z) | (rne16(p.w) << 16);
            u.z = rne16(q.x) | (rne16(q.y) << 16);
            u.w = rne16(q.z) | (rne16(q.w) << 16);
            dst[i >> 3] = u;
        }
        r0 = r0 + p.x * p.x; r1 = r1 + p.y * p.y;
        r2 = r2 + p.z * p.z; r3 = r3 + p.w * p.w;
        r4 = r4 + q.x * q.x; r5 = r5 + q.y * q.y;
        r6 = r6 + q.z * q.z; r7 = r7 + q.w * q.w;
    }
    float half = ((r0 + r1) + (r2 + r3)) + ((r4 + r5) + (r6 + r7));
    float other = __shfl_xor(half, 1, 64);
    if (h == 0) out[r] = half + other;
}

// ---------------------------------------------------------------------------
// Phase 1: bf16 MFMA score GEMM + per-row running max + candidate collection.
// CO-RESIDENCY config: 128x256 tile, 8 waves (512 thr) in 2x4 grid, 64x64
// per wave (acc[4][4] = 64 AGPR, 128 regs total -> 2 waves/SIMD per block),
// LDS 50 KiB -> TWO blocks co-resident per CU: when one block drains at its
// barrier the other keeps the MFMA pipe fed (m114 overlap).
// BK=32 double-buffer + 1-deep prefetch; R14-proven swizzle (0 conflicts):
// physical chunk = logical ^ ((row>>1)&3) on 16B units in 64B rows.
// Epilogue: wave-local 64-col max -> auxm[4][128] -> threads 0-127 merge ->
// ONE atomicMax/row -> threshold append.
// ---------------------------------------------------------------------------
__global__ __launch_bounds__(512, 4) void score_collect(
    const unsigned short* __restrict__ xbf,
    const unsigned short* __restrict__ cbbf,
    unsigned int* __restrict__ gmax,
    unsigned int* __restrict__ ccnt,
    unsigned short* __restrict__ cand)
{
    __shared__ unsigned char lds[51200];    // buf0 @0, buf1 @24K (A 8K + B 16K), aux @48K
    float* auxm = (float*)(lds + 49152);    // [4][128]
    const int t = threadIdx.x;
    const int l = t & 63, w = t >> 6;       // 8 waves
    const int g = l >> 4, c = l & 15;
    const int wr = w >> 2, wc = w & 3;      // 2x4 wave grid: 128 rows x 256 cols
    const int bid = blockIdx.x;             // 8192 blocks = 256 bx x 32 by
    const int xcd = bid & 7, idx = bid >> 3;
    const int bx = xcd + 8 * (idx & 31);    // 0..255, XCD-bijective
    const int by = idx >> 5;                // 0..31
    const int row0 = bx * 128;
    const int col0 = by * 256;

    f32x4 acc[4][4];
    #pragma unroll
    for (int m = 0; m < 4; ++m)
        #pragma unroll
        for (int n = 0; n < 4; ++n) acc[m][n] = (f32x4){0.f, 0.f, 0.f, 0.f};

    const char* xg = (const char*)xbf  + (size_t)row0 * 512;
    const char* cg = (const char*)cbbf + (size_t)col0 * 512;

    // stage s covers k-bytes [s*64, +64) of each row; A 1 + B 2 gl_lds/thread
#define STAGE(buf, ks)                                                         \
    do {                                                                       \
        const int kb_ = (ks) * 64;                                             \
        unsigned char* la_ = lds + (buf) * 24576;                              \
        {   /* A: 128 rows x 4 chunks = 512 = one per thread */                \
            int row_ = t >> 2, pc_ = t & 3;                                    \
            int sz_ = (row_ >> 1) & 3;                                         \
            gl_lds16(xg + (size_t)row_ * 512 + kb_ + ((pc_ ^ sz_) * 16),       \
                     la_ + t * 16);                                            \
        }                                                                      \
        _Pragma("unroll")                                                      \
        for (int r_ = 0; r_ < 2; ++r_) {  /* B: 256 rows x 4 chunks = 1024 */  \
            int i_ = r_ * 512 + t;                                             \
            int row_ = i_ >> 2, pc_ = i_ & 3;                                  \
            int sz_ = (row_ >> 1) & 3;                                         \
            gl_lds16(cg + (size_t)row_ * 512 + kb_ + ((pc_ ^ sz_) * 16),       \
                     la_ + 8192 + i_ * 16);                                    \
        }                                                                      \
    } while (0)

#define COMPUTE(buf)                                                           \
    do {                                                                       \
        const unsigned char* la_ = lds + (buf) * 24576;                        \
        const unsigned char* lb_ = la_ + 8192;                                 \
        const int swq_ = (g ^ ((c >> 1) & 3)) * 16;                            \
        short8v af[4], bv[4];                                                  \
        _Pragma("unroll")                                                      \
        for (int m = 0; m < 4; ++m)                                            \
            af[m] = *(const short8v*)(la_ + (64 * wr + 16 * m + c) * 64 + swq_); \
        _Pragma("unroll")                                                      \
        for (int n = 0; n < 4; ++n)                                            \
            bv[n] = *(const short8v*)(lb_ + (64 * wc + 16 * n + c) * 64 + swq_); \
        _Pragma("unroll")                                                      \
        for (int m = 0; m < 4; ++m)                                            \
            _Pragma("unroll")                                                  \
            for (int n = 0; n < 4; ++n)                                        \
                acc[m][n] = __builtin_amdgcn_mfma_f32_16x16x32_bf16(           \
                    af[m], bv[n], acc[m][n], 0, 0, 0);                         \
    } while (0)

    STAGE(0, 0);
    asm volatile("s_waitcnt vmcnt(0)" ::: "memory");
    __syncthreads();

    #pragma unroll
    for (int s = 0; s < 8; ++s) {
        if (s < 7) STAGE((s + 1) & 1, s + 1);          // prefetch next K-step
        COMPUTE(s & 1);
        asm volatile("s_waitcnt vmcnt(0)" ::: "memory");
        __syncthreads();
    }
#undef STAGE
#undef COMPUTE

    // ---- epilogue: C/D layout col = c, row = 4*g + j within each 16x16 ----
    // 1) wave-local 64-col max per row -> auxm[wc][row] (rows 0..127)
    #pragma unroll
    for (int m = 0; m < 4; ++m)
        #pragma unroll
        for (int j = 0; j < 4; ++j) {
            float v = acc[m][0][j];
            #pragma unroll
            for (int n = 1; n < 4; ++n) v = fmaxf(v, acc[m][n][j]);
            #pragma unroll
            for (int msk = 1; msk < 16; msk <<= 1)
                v = fmaxf(v, __shfl_xor(v, msk, 64));
            if (c == 0) auxm[wc * 128 + 64 * wr + 16 * m + 4 * g + j] = v;
        }
    __syncthreads();

    // 2) threads 0-127: merge 4 col-wave maxes, ONE atomicMax per row
    if (t < 128) {
        float vm = fmaxf(fmaxf(auxm[t], auxm[128 + t]),
                         fmaxf(auxm[256 + t], auxm[384 + t]));
        unsigned int ou = atomicMax(&gmax[row0 + t], mono_f32(vm));
        auxm[t] = fmaxf(vm, invmono_f32(ou));          // running global max
    }
    __syncthreads();

    // 3) all waves: threshold = running global max - margin; append candidates
    #pragma unroll
    for (int m = 0; m < 4; ++m)
        #pragma unroll
        for (int j = 0; j < 4; ++j) {
            int lrow = 64 * wr + 16 * m + 4 * g + j;
            float thr = auxm[lrow] - MARGIN;
            #pragma unroll
            for (int n = 0; n < 4; ++n) {
                float s = acc[m][n][j];
                if (s >= thr) {
                    int row = row0 + lrow;
                    unsigned int idx2 = atomicAdd(&ccnt[row], 1u);
                    if (idx2 < CAP)
                        cand[((size_t)row << 6) + idx2] =
                            (unsigned short)(col0 + 64 * wc + 16 * n + c);
                }
            }
        }
}

// ---------------------------------------------------------------------------
// Exact np-chain distance: ascending-k fp32 fmaf chain (BLAS order).
// ---------------------------------------------------------------------------
__device__ __forceinline__ unsigned long long np_dist_pack(
    const float4* __restrict__ xr4, const float* __restrict__ cb,
    int k, float X2, const float* __restrict__ c2)
{
    #pragma clang fp contract(off)
    const float4* cr4 = (const float4*)(cb + (size_t)k * DIM);
    float a = 0.f;
    #pragma unroll 8
    for (int t4 = 0; t4 < DIM / 4; ++t4) {
        float4 xv = xr4[t4];
        float4 cv = cr4[t4];
        a = fmaf(xv.x, cv.x, a);
        a = fmaf(xv.y, cv.y, a);
        a = fmaf(xv.z, cv.z, a);
        a = fmaf(xv.w, cv.w, a);
    }
    float u  = X2 - 2.0f * a;
    float dd = u + c2[k];
    return ((unsigned long long)mono_f32(dd) << 32) | (unsigned int)k;
}

// ---------------------------------------------------------------------------
// Phase 2: exact rescore of candidates. One wave per row, lane = candidate.
// ---------------------------------------------------------------------------
__global__ __launch_bounds__(256) void exact_select(
    const float* __restrict__ x, const float* __restrict__ cb,
    const float* __restrict__ x2, const float* __restrict__ c2,
    const unsigned int* __restrict__ ccnt, const unsigned short* __restrict__ cand,
    unsigned long long* __restrict__ best)
{
    const int l = threadIdx.x & 63;
    const int row = (blockIdx.x * 256 + threadIdx.x) >> 6;
    const unsigned int cnt = ccnt[row];
    const float4* xr4 = (const float4*)(x + (size_t)row * DIM);
    const float X2 = x2[row];
    unsigned long long bp = ~0ull;

    if (cnt <= CAP) {
        if (l < (int)cnt) {
            int k = (int)cand[((size_t)row << 6) + l];
            bp = np_dist_pack(xr4, cb, k, X2, c2);
        }
    } else {
        for (int k = l; k < KCB; k += 64) {
            unsigned long long pk = np_dist_pack(xr4, cb, k, X2, c2);
            if (pk < bp) bp = pk;
        }
    }
    #pragma unroll
    for (int m = 1; m < 64; m <<= 1) {
        unsigned long long v = shfl_xor_u64(bp, m);
        if (v < bp) bp = v;
    }
    if (l == 0) best[row] = bp;
}

// ---------------------------------------------------------------------------
// fp32 fallback score kernel (used only if ws is too small)
// ---------------------------------------------------------------------------
__global__ __launch_bounds__(256, 4) void score_argmin(const float* __restrict__ x,
                                                       const float* __restrict__ cb,
                                                       const float* __restrict__ c2,
                                                       const float* __restrict__ x2,
                                                       unsigned long long* __restrict__ best) {
    #pragma clang fp contract(off)
    __shared__ float As[16][128];
    __shared__ float Bs[16][128];
    const int row0 = blockIdx.x * 128;
    const int col0 = blockIdx.y * 128;
    const int t = threadIdx.x;
    const int tn = t & 15, tm = t >> 4;
    const int lrow = t >> 1, lseg = (t & 1) * 4;
    float acc[8][8];
    #pragma unroll
    for (int i = 0; i < 8; ++i)
        #pragma unroll
        for (int j = 0; j < 8; ++j) acc[i][j] = 0.f;
    const float* xp = x  + (size_t)(row0 + lrow) * DIM + lseg;
    const float* cp = cb + (size_t)(col0 + lrow) * DIM + lseg;
    for (int k0 = 0; k0 < DIM; k0 += 16) {
        float4 a0 = *(const float4*)(xp + k0);
        float4 a1 = *(const float4*)(xp + k0 + 8);
        float4 b0 = *(const float4*)(cp + k0);
        float4 b1 = *(const float4*)(cp + k0 + 8);
        __syncthreads();
        As[lseg + 0][lrow] = a0.x; As[lseg + 1][lrow] = a0.y;
        As[lseg + 2][lrow] = a0.z; As[lseg + 3][lrow] = a0.w;
        As[8 + lseg + 0][lrow] = a1.x; As[8 + lseg + 1][lrow] = a1.y;
        As[8 + lseg + 2][lrow] = a1.z; As[8 + lseg + 3][lrow] = a1.w;
        Bs[lseg + 0][lrow] = b0.x; Bs[lseg + 1][lrow] = b0.y;
        Bs[lseg + 2][lrow] = b0.z; Bs[lseg + 3][lrow] = b0.w;
        Bs[8 + lseg + 0][lrow] = b1.x; Bs[8 + lseg + 1][lrow] = b1.y;
        Bs[8 + lseg + 2][lrow] = b1.z; Bs[8 + lseg + 3][lrow] = b1.w;
        __syncthreads();
        #pragma unroll
        for (int kk = 0; kk < 16; ++kk) {
            float a[8], b[8];
            *(float4*)(a)     = *(const float4*)&As[kk][tm * 4];
            *(float4*)(a + 4) = *(const float4*)&As[kk][64 + tm * 4];
            *(float4*)(b)     = *(const float4*)&Bs[kk][tn * 4];
            *(float4*)(b + 4) = *(const float4*)&Bs[kk][64 + tn * 4];
            #pragma unroll
            for (int i = 0; i < 8; ++i)
                #pragma unroll
                for (int j = 0; j < 8; ++j)
                    acc[i][j] = fmaf(a[i], b[j], acc[i][j]);
        }
    }
    float c2v[8], x2v[8];
    #pragma unroll
    for (int j = 0; j < 4; ++j) {
        c2v[j]     = c2[col0 + tn * 4 + j];
        c2v[4 + j] = c2[col0 + 64 + tn * 4 + j];
    }
    #pragma unroll
    for (int i = 0; i < 4; ++i) {
        x2v[i]     = x2[row0 + tm * 4 + i];
        x2v[4 + i] = x2[row0 + 64 + tm * 4 + i];
    }
    #pragma unroll
    for (int i = 0; i < 8; ++i) {
        unsigned long long bp = ~0ull;
        #pragma unroll
        for (int j = 0; j < 8; ++j) {
            float tt = 2.0f * acc[i][j];
            float u  = x2v[i] - tt;
            float dd = u + c2v[j];
            int id = col0 + ((j < 4) ? (tn * 4 + j) : (64 + tn * 4 + (j - 4)));
            unsigned long long pk = ((unsigned long long)mono_f32(dd) << 32) | (unsigned int)id;
            if (pk < bp) bp = pk;
        }
        #pragma unroll
        for (int m = 1; m < 16; m <<= 1) {
            unsigned long long v = shfl_xor_u64(bp, m);
            if (v < bp) bp = v;
        }
        if (tn == 0) {
            int gr = row0 + ((i < 4) ? (tm * 4 + i) : (64 + tm * 4 + (i - 4)));
            atomicMin(&best[gr], bp);
        }
    }
}

// ---------------------------------------------------------------------------
// finalize: 16 rows per block; gather q, write quantized + ids(float),
// per-block loss partial (no atomics).
// ---------------------------------------------------------------------------
__global__ __launch_bounds__(256) void finalize(const float* __restrict__ x,
                                                const float* __restrict__ cb,
                                                const unsigned long long* __restrict__ best,
                                                float* __restrict__ out,
                                                float* __restrict__ partial) {
    __shared__ float rsum[16];
    const int t = threadIdx.x;
    const int rloc = t >> 4, seg = t & 15;
    const int r = blockIdx.x * 16 + rloc;
    const int id = (int)(best[r] & 0xFFFFFFFFu);
    const float4* xp = (const float4*)(x  + (size_t)r  * DIM) + seg * 4;
    const float4* cp = (const float4*)(cb + (size_t)id * DIM) + seg * 4;
    float4*       op = (float4*)(out + (size_t)r * DIM) + seg * 4;
    float s = 0.f;
    #pragma unroll
    for (int i = 0; i < 4; ++i) {
        float4 xv = xp[i], qv = cp[i];
        op[i] = qv;
        float dx = xv.x - qv.x, dy = xv.y - qv.y;
        float dz = xv.z - qv.z, dw = xv.w - qv.w;
        s += dx * dx + dy * dy + dz * dz + dw * dw;
    }
    #pragma unroll
    for (int m = 1; m < 16; m <<= 1) s += __shfl_xor(s, m, 64);
    if (seg == 0) {
        rsum[rloc] = s;
        out[(size_t)N_TOK * DIM + r] = (float)id;
    }
    __syncthreads();
    if (t == 0) {
        float bs = 0.f;
        #pragma unroll
        for (int i = 0; i < 16; ++i) bs += rsum[i];
        partial[blockIdx.x] = bs;
    }
}

// single block: sum 2048 partials, write loss scalar
__global__ __launch_bounds__(256) void reduce_loss(const float* __restrict__ partial,
                                                   float* __restrict__ out) {
    float s = 0.f;
    for (int i = threadIdx.x; i < 2048 / 4; i += 256) {
        float4 v = ((const float4*)partial)[i];
        s += (v.x + v.y) + (v.z + v.w);
    }
    #pragma unroll
    for (int o = 32; o > 0; o >>= 1) s += __shfl_down(s, o, 64);
    __shared__ float w4[4];
    if ((threadIdx.x & 63) == 0) w4[threadIdx.x >> 6] = s;
    __syncthreads();
    if (threadIdx.x == 0)
        out[(size_t)N_TOK * DIM + N_TOK] =
            (w4[0] + w4[1] + w4[2] + w4[3]) * (1.25f / ((float)N_TOK * (float)DIM));
}

// ---------------------------------------------------------------------------
extern "C" void kernel_launch(void* const* d_in, const int* in_sizes, int n_in,
                              void* d_out, int out_size, void* d_ws, size_t ws_size,
                              hipStream_t stream) {
    const float* x     = (const float*)d_in[0];
    const float* emb   = (const float*)d_in[1];
    const float* w_out = (const float*)d_in[2];
    float* out = (float*)d_out;

    char* ws = (char*)d_ws;
    unsigned long long* best = (unsigned long long*)ws;              //        0 (256 KiB)
    float* x2 = (float*)(ws + 262400);                               //   262400
    float* wT = (float*)(ws + 393472);                               //   393472 (reused as loss partial)
    float* cb = (float*)(ws + 655616);                               //   655616 (8 MiB)
    float* c2 = (float*)(ws + 9044224);                              //  9044224
    unsigned int*   gmax = (unsigned int*)(ws + 9076992);            //  9076992 (128 KiB)
    unsigned int*   ccnt = (unsigned int*)(ws + 9208064);            //  9208064 (128 KiB)
    unsigned short* cand = (unsigned short*)(ws + 9339136);          //  9339136 (4 MiB)
    unsigned short* xbf  = (unsigned short*)(ws + 13533440);         // 13533440 (16 MiB)
    unsigned short* cbbf = (unsigned short*)(ws + 30310656);         // 30310656 (4 MiB)
    float* partial = wT;                                             // 8 KiB, reuse
    const size_t NEED = 34504960;
    const bool useMfma = (ws_size >= NEED);

    transpose_w   <<<64,  256, 0, stream>>>(w_out, wT);
    build_codebook<<<KCB / KPB, 256, 0, stream>>>(emb, wT, cb);
    sumsq_np_bf   <<<N_TOK * 2 / 256, 256, 0, stream>>>(x, x2,
                      useMfma ? (uint4*)xbf : (uint4*)0);
    sumsq_np_bf   <<<KCB * 2 / 256, 256, 0, stream>>>(cb, c2,
                      useMfma ? (uint4*)cbbf : (uint4*)0);

    if (useMfma) {
        hipMemsetAsync(gmax, 0, 262144, stream);   // gmax + ccnt contiguous
        score_collect <<<8192, 512, 0, stream>>>(xbf, cbbf, gmax, ccnt, cand);
        exact_select  <<<N_TOK / 4, 256, 0, stream>>>(x, cb, x2, c2, ccnt, cand, best);
    } else {
        hipMemsetAsync(best, 0xFF, 262144, stream);
        score_argmin  <<<dim3(N_TOK / 128, KCB / 128), 256, 0, stream>>>(x, cb, c2, x2, best);
    }

    finalize      <<<N_TOK / 16, 256, 0, stream>>>(x, cb, best, out, partial);
    reduce_loss   <<<1, 256, 0, stream>>>(partial, out);
}

// Round 17
// 434.487 us; speedup vs baseline: 1.2238x; 1.0668x over previous
//
#include <hip/hip_runtime.h>
#include <hip/hip_bf16.h>

#define N_TOK 32768
#define DIM   256
#define KCB   8192
#define CAP   64
#define MARGIN 1.75e-4f

typedef __attribute__((ext_vector_type(8))) short short8v;   // 8 bf16
typedef __attribute__((ext_vector_type(4))) float f32x4;

__device__ __forceinline__ unsigned int mono_f32(float f) {
    unsigned int u = __float_as_uint(f);
    return (u >> 31) ? ~u : (u | 0x80000000u);
}
__device__ __forceinline__ float invmono_f32(unsigned int m) {
    unsigned int u = (m & 0x80000000u) ? (m & 0x7FFFFFFFu) : ~m;
    return __uint_as_float(u);
}
__device__ __forceinline__ unsigned long long shfl_xor_u64(unsigned long long v, int m) {
    unsigned int lo = (unsigned int)v, hi = (unsigned int)(v >> 32);
    lo = __shfl_xor(lo, m, 64);
    hi = __shfl_xor(hi, m, 64);
    return ((unsigned long long)hi << 32) | lo;
}
__device__ __forceinline__ void gl_lds16(const void* g, void* l) {
    __builtin_amdgcn_global_load_lds(
        (const __attribute__((address_space(1))) unsigned int*)g,
        (__attribute__((address_space(3))) unsigned int*)l, 16, 0, 0);
}
__device__ __forceinline__ unsigned int rne16(float f) {
    unsigned int b = __float_as_uint(f);
    return (b + 0x7FFFu + ((b >> 16) & 1u)) >> 16;
}

// ---------------------------------------------------------------------------
// fused_pre: blocks 0..63 transpose w_out -> wT; blocks 64..319 do numpy
// pairwise sum-of-squares of x rows (exact np order) + fp32->bf16 cast.
// ---------------------------------------------------------------------------
__global__ __launch_bounds__(256) void fused_pre(const float* __restrict__ w,
                                                 float* __restrict__ wT,
                                                 const float* __restrict__ x,
                                                 float* __restrict__ x2,
                                                 uint4* __restrict__ xbf) {
    #pragma clang fp contract(off)
    __shared__ float tile[32][33];
    const int t = threadIdx.x;
    if (blockIdx.x < 64) {
        int bx = blockIdx.x & 7, by = blockIdx.x >> 3;
        int x0 = bx * 32, y0 = by * 32;
        int tx = t & 31, ty = t >> 5;
        #pragma unroll
        for (int i = 0; i < 32; i += 8)
            tile[ty + i][tx] = w[(y0 + ty + i) * DIM + x0 + tx];
        __syncthreads();
        #pragma unroll
        for (int i = 0; i < 32; i += 8)
            wT[(x0 + ty + i) * DIM + y0 + tx] = tile[tx][ty + i];
        return;
    }
    int idx = (blockIdx.x - 64) * 256 + t;
    int r = idx >> 1, h = idx & 1;
    const float* b = x + (size_t)r * DIM + h * 128;
    uint4* dst = xbf + ((size_t)r * 32 + h * 16);
    float r0 = 0.f, r1 = 0.f, r2 = 0.f, r3 = 0.f,
          r4 = 0.f, r5 = 0.f, r6 = 0.f, r7 = 0.f;
    #pragma unroll
    for (int i = 0; i < 128; i += 8) {
        float4 p = *(const float4*)(b + i);
        float4 q = *(const float4*)(b + i + 4);
        uint4 u;
        u.x = rne16(p.x) | (rne16(p.y) << 16);
        u.y = rne16(p.z) | (rne16(p.w) << 16);
        u.z = rne16(q.x) | (rne16(q.y) << 16);
        u.w = rne16(q.z) | (rne16(q.w) << 16);
        dst[i >> 3] = u;
        r0 = r0 + p.x * p.x; r1 = r1 + p.y * p.y;
        r2 = r2 + p.z * p.z; r3 = r3 + p.w * p.w;
        r4 = r4 + q.x * q.x; r5 = r5 + q.y * q.y;
        r6 = r6 + q.z * q.z; r7 = r7 + q.w * q.w;
    }
    float half = ((r0 + r1) + (r2 + r3)) + ((r4 + r5) + (r6 + r7));
    float other = __shfl_xor(half, 1, 64);
    if (h == 0) x2[r] = half + other;
}

// ---------------------------------------------------------------------------
// codebook[k][d] = sum_j emb[k][j]*w_out[d][j], sequential-j FMA chain (BLAS order)
// ---------------------------------------------------------------------------
#define KPB 8
__global__ __launch_bounds__(256) void build_codebook(const float* __restrict__ emb,
                                                      const float* __restrict__ wT,
                                                      float* __restrict__ cb) {
    __shared__ float e[KPB][DIM];
    const int k0 = blockIdx.x * KPB;
    const int t = threadIdx.x;
    for (int i = t; i < KPB * DIM / 4; i += 256)
        ((float4*)&e[0][0])[i] = ((const float4*)(emb + (size_t)k0 * DIM))[i];
    __syncthreads();
    const int d = t;
    float acc[KPB];
    #pragma unroll
    for (int kk = 0; kk < KPB; ++kk) acc[kk] = 0.f;
    for (int j = 0; j < DIM; ++j) {
        float w = wT[j * DIM + d];
        #pragma unroll
        for (int kk = 0; kk < KPB; ++kk)
            acc[kk] = fmaf(e[kk][j], w, acc[kk]);
    }
    #pragma unroll
    for (int kk = 0; kk < KPB; ++kk)
        cb[(size_t)(k0 + kk) * DIM + d] = acc[kk];
}

// ---------------------------------------------------------------------------
// numpy pairwise sum-of-squares (exact np order), 2 threads per row,
// FUSED with fp32->bf16 (RNE) conversion (bfout != null). Used for cb.
// ---------------------------------------------------------------------------
__global__ __launch_bounds__(256) void sumsq_np_bf(const float* __restrict__ a,
                                                   float* __restrict__ out,
                                                   uint4* __restrict__ bfout) {
    #pragma clang fp contract(off)
    int idx = blockIdx.x * 256 + threadIdx.x;
    int r = idx >> 1, h = idx & 1;
    const float* b = a + (size_t)r * DIM + h * 128;
    uint4* dst = bfout ? bfout + ((size_t)r * 32 + h * 16) : (uint4*)0;
    float r0 = 0.f, r1 = 0.f, r2 = 0.f, r3 = 0.f,
          r4 = 0.f, r5 = 0.f, r6 = 0.f, r7 = 0.f;
    #pragma unroll
    for (int i = 0; i < 128; i += 8) {
        float4 p = *(const float4*)(b + i);
        float4 q = *(const float4*)(b + i + 4);
        if (bfout) {
            uint4 u;
            u.x = rne16(p.x) | (rne16(p.y) << 16);
            u.y = rne16(p.z) | (rne16(p.w) << 16);
            u.z = rne16(q.x) | (rne16(q.y) << 16);
            u.w = rne16(q.z) | (rne16(q.w) << 16);
            dst[i >> 3] = u;
        }
        r0 = r0 + p.x * p.x; r1 = r1 + p.y * p.y;
        r2 = r2 + p.z * p.z; r3 = r3 + p.w * p.w;
        r4 = r4 + q.x * q.x; r5 = r5 + q.y * q.y;
        r6 = r6 + q.z * q.z; r7 = r7 + q.w * q.w;
    }
    float half = ((r0 + r1) + (r2 + r3)) + ((r4 + r5) + (r6 + r7));
    float other = __shfl_xor(half, 1, 64);
    if (h == 0) out[r] = half + other;
}

// ---------------------------------------------------------------------------
// Phase 1: bf16 MFMA score GEMM + per-row running max + candidate collection.
// R15 structure (proven): 128x256 tile, 8 waves 2x4, 64x64/wave, 2 blocks/CU,
// BK=32 dbuf + prefetch, conflict-free swizzle, s_setprio around MFMA.
// ---------------------------------------------------------------------------
__global__ __launch_bounds__(512, 4) void score_collect(
    const unsigned short* __restrict__ xbf,
    const unsigned short* __restrict__ cbbf,
    unsigned int* __restrict__ gmax,
    unsigned int* __restrict__ ccnt,
    unsigned short* __restrict__ cand)
{
    __shared__ unsigned char lds[51200];    // buf0 @0, buf1 @24K (A 8K + B 16K), aux @48K
    float* auxm = (float*)(lds + 49152);    // [4][128]
    const int t = threadIdx.x;
    const int l = t & 63, w = t >> 6;
    const int g = l >> 4, c = l & 15;
    const int wr = w >> 2, wc = w & 3;      // 2x4 wave grid: 128 rows x 256 cols
    const int bid = blockIdx.x;             // 8192 blocks = 256 bx x 32 by
    const int xcd = bid & 7, idx = bid >> 3;
    const int bx = xcd + 8 * (idx & 31);
    const int by = idx >> 5;
    const int row0 = bx * 128;
    const int col0 = by * 256;

    f32x4 acc[4][4];
    #pragma unroll
    for (int m = 0; m < 4; ++m)
        #pragma unroll
        for (int n = 0; n < 4; ++n) acc[m][n] = (f32x4){0.f, 0.f, 0.f, 0.f};

    const char* xg = (const char*)xbf  + (size_t)row0 * 512;
    const char* cg = (const char*)cbbf + (size_t)col0 * 512;

#define STAGE(buf, ks)                                                         \
    do {                                                                       \
        const int kb_ = (ks) * 64;                                             \
        unsigned char* la_ = lds + (buf) * 24576;                              \
        {   /* A: 128 rows x 4 chunks = 512 = one per thread */                \
            int row_ = t >> 2, pc_ = t & 3;                                    \
            int sz_ = (row_ >> 1) & 3;                                         \
            gl_lds16(xg + (size_t)row_ * 512 + kb_ + ((pc_ ^ sz_) * 16),       \
                     la_ + t * 16);                                            \
        }                                                                      \
        _Pragma("unroll")                                                      \
        for (int r_ = 0; r_ < 2; ++r_) {  /* B: 256 rows x 4 chunks = 1024 */  \
            int i_ = r_ * 512 + t;                                             \
            int row_ = i_ >> 2, pc_ = i_ & 3;                                  \
            int sz_ = (row_ >> 1) & 3;                                         \
            gl_lds16(cg + (size_t)row_ * 512 + kb_ + ((pc_ ^ sz_) * 16),       \
                     la_ + 8192 + i_ * 16);                                    \
        }                                                                      \
    } while (0)

#define COMPUTE(buf)                                                           \
    do {                                                                       \
        const unsigned char* la_ = lds + (buf) * 24576;                        \
        const unsigned char* lb_ = la_ + 8192;                                 \
        const int swq_ = (g ^ ((c >> 1) & 3)) * 16;                            \
        short8v af[4], bv[4];                                                  \
        _Pragma("unroll")                                                      \
        for (int m = 0; m < 4; ++m)                                            \
            af[m] = *(const short8v*)(la_ + (64 * wr + 16 * m + c) * 64 + swq_); \
        _Pragma("unroll")                                                      \
        for (int n = 0; n < 4; ++n)                                            \
            bv[n] = *(const short8v*)(lb_ + (64 * wc + 16 * n + c) * 64 + swq_); \
        __builtin_amdgcn_s_setprio(1);                                         \
        _Pragma("unroll")                                                      \
        for (int m = 0; m < 4; ++m)                                            \
            _Pragma("unroll")                                                  \
            for (int n = 0; n < 4; ++n)                                        \
                acc[m][n] = __builtin_amdgcn_mfma_f32_16x16x32_bf16(           \
                    af[m], bv[n], acc[m][n], 0, 0, 0);                         \
        __builtin_amdgcn_s_setprio(0);                                         \
    } while (0)

    STAGE(0, 0);
    asm volatile("s_waitcnt vmcnt(0)" ::: "memory");
    __syncthreads();

    #pragma unroll
    for (int s = 0; s < 8; ++s) {
        if (s < 7) STAGE((s + 1) & 1, s + 1);          // prefetch next K-step
        COMPUTE(s & 1);
        asm volatile("s_waitcnt vmcnt(0)" ::: "memory");
        __syncthreads();
    }
#undef STAGE
#undef COMPUTE

    // ---- epilogue: C/D layout col = c, row = 4*g + j within each 16x16 ----
    #pragma unroll
    for (int m = 0; m < 4; ++m)
        #pragma unroll
        for (int j = 0; j < 4; ++j) {
            float v = acc[m][0][j];
            #pragma unroll
            for (int n = 1; n < 4; ++n) v = fmaxf(v, acc[m][n][j]);
            #pragma unroll
            for (int msk = 1; msk < 16; msk <<= 1)
                v = fmaxf(v, __shfl_xor(v, msk, 64));
            if (c == 0) auxm[wc * 128 + 64 * wr + 16 * m + 4 * g + j] = v;
        }
    __syncthreads();

    if (t < 128) {
        float vm = fmaxf(fmaxf(auxm[t], auxm[128 + t]),
                         fmaxf(auxm[256 + t], auxm[384 + t]));
        unsigned int ou = atomicMax(&gmax[row0 + t], mono_f32(vm));
        auxm[t] = fmaxf(vm, invmono_f32(ou));
    }
    __syncthreads();

    #pragma unroll
    for (int m = 0; m < 4; ++m)
        #pragma unroll
        for (int j = 0; j < 4; ++j) {
            int lrow = 64 * wr + 16 * m + 4 * g + j;
            float thr = auxm[lrow] - MARGIN;
            #pragma unroll
            for (int n = 0; n < 4; ++n) {
                float s = acc[m][n][j];
                if (s >= thr) {
                    int row = row0 + lrow;
                    unsigned int idx2 = atomicAdd(&ccnt[row], 1u);
                    if (idx2 < CAP)
                        cand[((size_t)row << 6) + idx2] =
                            (unsigned short)(col0 + 64 * wc + 16 * n + c);
                }
            }
        }
}

// ---------------------------------------------------------------------------
// Exact np-chain distance: ascending-k fp32 fmaf chain (BLAS order).
// ---------------------------------------------------------------------------
__device__ __forceinline__ unsigned long long np_dist_pack(
    const float4* __restrict__ xr4, const float* __restrict__ cb,
    int k, float X2, const float* __restrict__ c2)
{
    #pragma clang fp contract(off)
    const float4* cr4 = (const float4*)(cb + (size_t)k * DIM);
    float a = 0.f;
    #pragma unroll 8
    for (int t4 = 0; t4 < DIM / 4; ++t4) {
        float4 xv = xr4[t4];
        float4 cv = cr4[t4];
        a = fmaf(xv.x, cv.x, a);
        a = fmaf(xv.y, cv.y, a);
        a = fmaf(xv.z, cv.z, a);
        a = fmaf(xv.w, cv.w, a);
    }
    float u  = X2 - 2.0f * a;
    float dd = u + c2[k];
    return ((unsigned long long)mono_f32(dd) << 32) | (unsigned int)k;
}

// ---------------------------------------------------------------------------
// Phase 2 FUSED: exact rescore + gather + output + loss partial. One wave
// per row (4 rows/block). After the packed-min butterfly every lane holds
// the winning id; each lane then handles exactly ONE float4 of the row
// (64 lanes x 16B = 256 floats): gather cb[id], write quantized + id,
// reduce squared-error partial.
// ---------------------------------------------------------------------------
__global__ __launch_bounds__(256) void select_finalize(
    const float* __restrict__ x, const float* __restrict__ cb,
    const float* __restrict__ x2, const float* __restrict__ c2,
    const unsigned int* __restrict__ ccnt, const unsigned short* __restrict__ cand,
    float* __restrict__ out, float* __restrict__ partial)
{
    __shared__ float wsum[4];
    const int t = threadIdx.x;
    const int l = t & 63, wv = t >> 6;
    const int row = blockIdx.x * 4 + wv;
    const unsigned int cnt = ccnt[row];
    const float4* xr4 = (const float4*)(x + (size_t)row * DIM);
    const float X2 = x2[row];
    unsigned long long bp = ~0ull;

    if (cnt <= CAP) {
        if (l < (int)cnt) {
            int k = (int)cand[((size_t)row << 6) + l];
            bp = np_dist_pack(xr4, cb, k, X2, c2);
        }
    } else {
        for (int k = l; k < KCB; k += 64) {
            unsigned long long pk = np_dist_pack(xr4, cb, k, X2, c2);
            if (pk < bp) bp = pk;
        }
    }
    #pragma unroll
    for (int m = 1; m < 64; m <<= 1) {
        unsigned long long v = shfl_xor_u64(bp, m);
        if (v < bp) bp = v;
    }
    const int id = (int)(bp & 0xFFFFFFFFu);

    // gather + write + loss: lane l handles float4 index l (row = 64 float4s)
    const float4* cp = (const float4*)(cb + (size_t)id * DIM);
    float4*       op = (float4*)(out + (size_t)row * DIM);
    float4 xv = xr4[l], qv = cp[l];
    op[l] = qv;
    float dx = xv.x - qv.x, dy = xv.y - qv.y;
    float dz = xv.z - qv.z, dw = xv.w - qv.w;
    float s = dx * dx + dy * dy + dz * dz + dw * dw;
    #pragma unroll
    for (int m = 1; m < 64; m <<= 1) s += __shfl_xor(s, m, 64);
    if (l == 0) {
        out[(size_t)N_TOK * DIM + row] = (float)id;
        wsum[wv] = s;
    }
    __syncthreads();
    if (t == 0)
        partial[blockIdx.x] = (wsum[0] + wsum[1]) + (wsum[2] + wsum[3]);
}

// ---------------------------------------------------------------------------
// fp32 fallback score kernel (used only if ws is too small)
// ---------------------------------------------------------------------------
__global__ __launch_bounds__(256, 4) void score_argmin(const float* __restrict__ x,
                                                       const float* __restrict__ cb,
                                                       const float* __restrict__ c2,
                                                       const float* __restrict__ x2,
                                                       unsigned long long* __restrict__ best) {
    #pragma clang fp contract(off)
    __shared__ float As[16][128];
    __shared__ float Bs[16][128];
    const int row0 = blockIdx.x * 128;
    const int col0 = blockIdx.y * 128;
    const int t = threadIdx.x;
    const int tn = t & 15, tm = t >> 4;
    const int lrow = t >> 1, lseg = (t & 1) * 4;
    float acc[8][8];
    #pragma unroll
    for (int i = 0; i < 8; ++i)
        #pragma unroll
        for (int j = 0; j < 8; ++j) acc[i][j] = 0.f;
    const float* xp = x  + (size_t)(row0 + lrow) * DIM + lseg;
    const float* cp = cb + (size_t)(col0 + lrow) * DIM + lseg;
    for (int k0 = 0; k0 < DIM; k0 += 16) {
        float4 a0 = *(const float4*)(xp + k0);
        float4 a1 = *(const float4*)(xp + k0 + 8);
        float4 b0 = *(const float4*)(cp + k0);
        float4 b1 = *(const float4*)(cp + k0 + 8);
        __syncthreads();
        As[lseg + 0][lrow] = a0.x; As[lseg + 1][lrow] = a0.y;
        As[lseg + 2][lrow] = a0.z; As[lseg + 3][lrow] = a0.w;
        As[8 + lseg + 0][lrow] = a1.x; As[8 + lseg + 1][lrow] = a1.y;
        As[8 + lseg + 2][lrow] = a1.z; As[8 + lseg + 3][lrow] = a1.w;
        Bs[lseg + 0][lrow] = b0.x; Bs[lseg + 1][lrow] = b0.y;
        Bs[lseg + 2][lrow] = b0.z; Bs[lseg + 3][lrow] = b0.w;
        Bs[8 + lseg + 0][lrow] = b1.x; Bs[8 + lseg + 1][lrow] = b1.y;
        Bs[8 + lseg + 2][lrow] = b1.z; Bs[8 + lseg + 3][lrow] = b1.w;
        __syncthreads();
        #pragma unroll
        for (int kk = 0; kk < 16; ++kk) {
            float a[8], b[8];
            *(float4*)(a)     = *(const float4*)&As[kk][tm * 4];
            *(float4*)(a + 4) = *(const float4*)&As[kk][64 + tm * 4];
            *(float4*)(b)     = *(const float4*)&Bs[kk][tn * 4];
            *(float4*)(b + 4) = *(const float4*)&Bs[kk][64 + tn * 4];
            #pragma unroll
            for (int i = 0; i < 8; ++i)
                #pragma unroll
                for (int j = 0; j < 8; ++j)
                    acc[i][j] = fmaf(a[i], b[j], acc[i][j]);
        }
    }
    float c2v[8], x2v[8];
    #pragma unroll
    for (int j = 0; j < 4; ++j) {
        c2v[j]     = c2[col0 + tn * 4 + j];
        c2v[4 + j] = c2[col0 + 64 + tn * 4 + j];
    }
    #pragma unroll
    for (int i = 0; i < 4; ++i) {
        x2v[i]     = x2[row0 + tm * 4 + i];
        x2v[4 + i] = x2[row0 + 64 + tm * 4 + i];
    }
    #pragma unroll
    for (int i = 0; i < 8; ++i) {
        unsigned long long bp = ~0ull;
        #pragma unroll
        for (int j = 0; j < 8; ++j) {
            float tt = 2.0f * acc[i][j];
            float u  = x2v[i] - tt;
            float dd = u + c2v[j];
            int id = col0 + ((j < 4) ? (tn * 4 + j) : (64 + tn * 4 + (j - 4)));
            unsigned long long pk = ((unsigned long long)mono_f32(dd) << 32) | (unsigned int)id;
            if (pk < bp) bp = pk;
        }
        #pragma unroll
        for (int m = 1; m < 16; m <<= 1) {
            unsigned long long v = shfl_xor_u64(bp, m);
            if (v < bp) bp = v;
        }
        if (tn == 0) {
            int gr = row0 + ((i < 4) ? (tm * 4 + i) : (64 + tm * 4 + (i - 4)));
            atomicMin(&best[gr], bp);
        }
    }
}

// ---------------------------------------------------------------------------
// fallback finalize (16 rows/block) — used only on the fp32 path
// ---------------------------------------------------------------------------
__global__ __launch_bounds__(256) void finalize(const float* __restrict__ x,
                                                const float* __restrict__ cb,
                                                const unsigned long long* __restrict__ best,
                                                float* __restrict__ out,
                                                float* __restrict__ partial) {
    __shared__ float rsum[16];
    const int t = threadIdx.x;
    const int rloc = t >> 4, seg = t & 15;
    const int r = blockIdx.x * 16 + rloc;
    const int id = (int)(best[r] & 0xFFFFFFFFu);
    const float4* xp = (const float4*)(x  + (size_t)r  * DIM) + seg * 4;
    const float4* cp = (const float4*)(cb + (size_t)id * DIM) + seg * 4;
    float4*       op = (float4*)(out + (size_t)r * DIM) + seg * 4;
    float s = 0.f;
    #pragma unroll
    for (int i = 0; i < 4; ++i) {
        float4 xv = xp[i], qv = cp[i];
        op[i] = qv;
        float dx = xv.x - qv.x, dy = xv.y - qv.y;
        float dz = xv.z - qv.z, dw = xv.w - qv.w;
        s += dx * dx + dy * dy + dz * dz + dw * dw;
    }
    #pragma unroll
    for (int m = 1; m < 16; m <<= 1) s += __shfl_xor(s, m, 64);
    if (seg == 0) {
        rsum[rloc] = s;
        out[(size_t)N_TOK * DIM + r] = (float)id;
    }
    __syncthreads();
    if (t == 0) {
        float bs = 0.f;
        #pragma unroll
        for (int i = 0; i < 16; ++i) bs += rsum[i];
        partial[blockIdx.x] = bs;
    }
}

// single block: sum n partials, write loss scalar
__global__ __launch_bounds__(256) void reduce_loss(const float* __restrict__ partial,
                                                   int n, float* __restrict__ out) {
    float s = 0.f;
    for (int i = threadIdx.x; i < n / 4; i += 256) {
        float4 v = ((const float4*)partial)[i];
        s += (v.x + v.y) + (v.z + v.w);
    }
    #pragma unroll
    for (int o = 32; o > 0; o >>= 1) s += __shfl_down(s, o, 64);
    __shared__ float w4[4];
    if ((threadIdx.x & 63) == 0) w4[threadIdx.x >> 6] = s;
    __syncthreads();
    if (threadIdx.x == 0)
        out[(size_t)N_TOK * DIM + N_TOK] =
            (w4[0] + w4[1] + w4[2] + w4[3]) * (1.25f / ((float)N_TOK * (float)DIM));
}

// ---------------------------------------------------------------------------
extern "C" void kernel_launch(void* const* d_in, const int* in_sizes, int n_in,
                              void* d_out, int out_size, void* d_ws, size_t ws_size,
                              hipStream_t stream) {
    const float* x     = (const float*)d_in[0];
    const float* emb   = (const float*)d_in[1];
    const float* w_out = (const float*)d_in[2];
    float* out = (float*)d_out;

    char* ws = (char*)d_ws;
    unsigned long long* best = (unsigned long long*)ws;              //        0 (256 KiB, fallback only)
    float* x2 = (float*)(ws + 262400);                               //   262400
    float* wT = (float*)(ws + 393472);                               //   393472 (reused as loss partial)
    float* cb = (float*)(ws + 655616);                               //   655616 (8 MiB)
    float* c2 = (float*)(ws + 9044224);                              //  9044224
    unsigned int*   gmax = (unsigned int*)(ws + 9076992);            //  9076992 (128 KiB)
    unsigned int*   ccnt = (unsigned int*)(ws + 9208064);            //  9208064 (128 KiB)
    unsigned short* cand = (unsigned short*)(ws + 9339136);          //  9339136 (4 MiB)
    unsigned short* xbf  = (unsigned short*)(ws + 13533440);         // 13533440 (16 MiB)
    unsigned short* cbbf = (unsigned short*)(ws + 30310656);         // 30310656 (4 MiB)
    float* partial = wT;                                             // 32 KiB, reuse
    const size_t NEED = 34504960;
    const bool useMfma = (ws_size >= NEED);

    if (useMfma) {
        hipMemsetAsync(gmax, 0, 262144, stream);   // gmax + ccnt contiguous
        fused_pre     <<<64 + N_TOK * 2 / 256, 256, 0, stream>>>(w_out, wT, x, x2, (uint4*)xbf);
        build_codebook<<<KCB / KPB, 256, 0, stream>>>(emb, wT, cb);
        sumsq_np_bf   <<<KCB * 2 / 256, 256, 0, stream>>>(cb, c2, (uint4*)cbbf);
        score_collect <<<8192, 512, 0, stream>>>(xbf, cbbf, gmax, ccnt, cand);
        select_finalize<<<N_TOK / 4, 256, 0, stream>>>(x, cb, x2, c2, ccnt, cand, out, partial);
        reduce_loss   <<<1, 256, 0, stream>>>(partial, N_TOK / 4, out);
    } else {
        hipMemsetAsync(best, 0xFF, 262144, stream);
        fused_pre     <<<64 + N_TOK * 2 / 256, 256, 0, stream>>>(w_out, wT, x, x2, (uint4*)xbf);
        build_codebook<<<KCB / KPB, 256, 0, stream>>>(emb, wT, cb);
        sumsq_np_bf   <<<KCB * 2 / 256, 256, 0, stream>>>(cb, c2, (uint4*)0);
        score_argmin  <<<dim3(N_TOK / 128, KCB / 128), 256, 0, stream>>>(x, cb, c2, x2, best);
        finalize      <<<N_TOK / 16, 256, 0, stream>>>(x, cb, best, out, partial);
        reduce_loss   <<<1, 256, 0, stream>>>(partial, N_TOK / 16, out);
    }
}

// Round 18
// 431.058 us; speedup vs baseline: 1.2335x; 1.0080x over previous
//
#include <hip/hip_runtime.h>
#include <hip/hip_bf16.h>

#define N_TOK 32768
#define DIM   256
#define KCB   8192
#define CAP   64
#define MARGIN 1.75e-4f

typedef __attribute__((ext_vector_type(8))) short short8v;   // 8 bf16
typedef __attribute__((ext_vector_type(4))) float f32x4;

__device__ __forceinline__ unsigned int mono_f32(float f) {
    unsigned int u = __float_as_uint(f);
    return (u >> 31) ? ~u : (u | 0x80000000u);
}
__device__ __forceinline__ float invmono_f32(unsigned int m) {
    unsigned int u = (m & 0x80000000u) ? (m & 0x7FFFFFFFu) : ~m;
    return __uint_as_float(u);
}
__device__ __forceinline__ unsigned long long shfl_xor_u64(unsigned long long v, int m) {
    unsigned int lo = (unsigned int)v, hi = (unsigned int)(v >> 32);
    lo = __shfl_xor(lo, m, 64);
    hi = __shfl_xor(hi, m, 64);
    return ((unsigned long long)hi << 32) | lo;
}
__device__ __forceinline__ void gl_lds16(const void* g, void* l) {
    __builtin_amdgcn_global_load_lds(
        (const __attribute__((address_space(1))) unsigned int*)g,
        (__attribute__((address_space(3))) unsigned int*)l, 16, 0, 0);
}
__device__ __forceinline__ unsigned int rne16(float f) {
    unsigned int b = __float_as_uint(f);
    return (b + 0x7FFFu + ((b >> 16) & 1u)) >> 16;
}

// ---------------------------------------------------------------------------
// fused_pre: blocks 0..63 transpose w_out -> wT; blocks 64..319 do numpy
// pairwise sum-of-squares of x rows (exact np order) + fp32->bf16 cast.
// ---------------------------------------------------------------------------
__global__ __launch_bounds__(256) void fused_pre(const float* __restrict__ w,
                                                 float* __restrict__ wT,
                                                 const float* __restrict__ x,
                                                 float* __restrict__ x2,
                                                 uint4* __restrict__ xbf) {
    #pragma clang fp contract(off)
    __shared__ float tile[32][33];
    const int t = threadIdx.x;
    if (blockIdx.x < 64) {
        int bx = blockIdx.x & 7, by = blockIdx.x >> 3;
        int x0 = bx * 32, y0 = by * 32;
        int tx = t & 31, ty = t >> 5;
        #pragma unroll
        for (int i = 0; i < 32; i += 8)
            tile[ty + i][tx] = w[(y0 + ty + i) * DIM + x0 + tx];
        __syncthreads();
        #pragma unroll
        for (int i = 0; i < 32; i += 8)
            wT[(x0 + ty + i) * DIM + y0 + tx] = tile[tx][ty + i];
        return;
    }
    int idx = (blockIdx.x - 64) * 256 + t;
    int r = idx >> 1, h = idx & 1;
    const float* b = x + (size_t)r * DIM + h * 128;
    uint4* dst = xbf + ((size_t)r * 32 + h * 16);
    float r0 = 0.f, r1 = 0.f, r2 = 0.f, r3 = 0.f,
          r4 = 0.f, r5 = 0.f, r6 = 0.f, r7 = 0.f;
    #pragma unroll
    for (int i = 0; i < 128; i += 8) {
        float4 p = *(const float4*)(b + i);
        float4 q = *(const float4*)(b + i + 4);
        uint4 u;
        u.x = rne16(p.x) | (rne16(p.y) << 16);
        u.y = rne16(p.z) | (rne16(p.w) << 16);
        u.z = rne16(q.x) | (rne16(q.y) << 16);
        u.w = rne16(q.z) | (rne16(q.w) << 16);
        dst[i >> 3] = u;
        r0 = r0 + p.x * p.x; r1 = r1 + p.y * p.y;
        r2 = r2 + p.z * p.z; r3 = r3 + p.w * p.w;
        r4 = r4 + q.x * q.x; r5 = r5 + q.y * q.y;
        r6 = r6 + q.z * q.z; r7 = r7 + q.w * q.w;
    }
    float half = ((r0 + r1) + (r2 + r3)) + ((r4 + r5) + (r6 + r7));
    float other = __shfl_xor(half, 1, 64);
    if (h == 0) x2[r] = half + other;
}

// ---------------------------------------------------------------------------
// build_codebook FUSED: cb = emb @ w_out.T (sequential-j fp32 FMA chain,
// BLAS order) + bf16 cast of cb + c2[k] in exact numpy pairwise order.
// The squares fl(cb^2) are staged in LDS and summed by 16 threads using the
// identical 8-accumulator/tree pattern sumsq_np_bf used — bit-identical c2.
// ---------------------------------------------------------------------------
#define KPB 8
__global__ __launch_bounds__(256) void build_codebook(const float* __restrict__ emb,
                                                      const float* __restrict__ wT,
                                                      float* __restrict__ cb,
                                                      float* __restrict__ c2,
                                                      unsigned short* __restrict__ cbbf) {
    #pragma clang fp contract(off)
    __shared__ float e[KPB][DIM];   // staging for emb rows, then reused for squares
    const int k0 = blockIdx.x * KPB;
    const int t = threadIdx.x;
    for (int i = t; i < KPB * DIM / 4; i += 256)
        ((float4*)&e[0][0])[i] = ((const float4*)(emb + (size_t)k0 * DIM))[i];
    __syncthreads();
    const int d = t;
    float acc[KPB];
    #pragma unroll
    for (int kk = 0; kk < KPB; ++kk) acc[kk] = 0.f;
    for (int j = 0; j < DIM; ++j) {
        float w = wT[j * DIM + d];
        #pragma unroll
        for (int kk = 0; kk < KPB; ++kk)
            acc[kk] = fmaf(e[kk][j], w, acc[kk]);
    }
    __syncthreads();                       // done reading e (emb rows)
    #pragma unroll
    for (int kk = 0; kk < KPB; ++kk) {
        cb[(size_t)(k0 + kk) * DIM + d] = acc[kk];
        if (cbbf)
            cbbf[(size_t)(k0 + kk) * DIM + d] = (unsigned short)rne16(acc[kk]);
        e[kk][d] = acc[kk] * acc[kk];      // fl(cb^2), same as numpy's a*a temp
    }
    __syncthreads();
    // threads 0..15: (kk = tt>>1, h = tt&1) -> np pairwise over 128 squares
    if (t < 16) {
        const int kk = t >> 1, h = t & 1;
        const float* b = &e[kk][h * 128];
        float r0 = 0.f, r1 = 0.f, r2 = 0.f, r3 = 0.f,
              r4 = 0.f, r5 = 0.f, r6 = 0.f, r7 = 0.f;
        #pragma unroll
        for (int i = 0; i < 128; i += 8) {
            r0 = r0 + b[i + 0]; r1 = r1 + b[i + 1];
            r2 = r2 + b[i + 2]; r3 = r3 + b[i + 3];
            r4 = r4 + b[i + 4]; r5 = r5 + b[i + 5];
            r6 = r6 + b[i + 6]; r7 = r7 + b[i + 7];
        }
        float half = ((r0 + r1) + (r2 + r3)) + ((r4 + r5) + (r6 + r7));
        float other = __shfl_xor(half, 1, 64);
        if (h == 0) c2[k0 + kk] = half + other;
    }
}

// ---------------------------------------------------------------------------
// Phase 1: bf16 MFMA score GEMM + per-row running max + candidate collection.
// R15/R17 proven structure: 128x256 tile, 8 waves 2x4, 64x64/wave, 2 blk/CU,
// BK=32 dbuf + prefetch, conflict-free swizzle, s_setprio around MFMA.
// ---------------------------------------------------------------------------
__global__ __launch_bounds__(512, 4) void score_collect(
    const unsigned short* __restrict__ xbf,
    const unsigned short* __restrict__ cbbf,
    unsigned int* __restrict__ gmax,
    unsigned int* __restrict__ ccnt,
    unsigned short* __restrict__ cand)
{
    __shared__ unsigned char lds[51200];    // buf0 @0, buf1 @24K (A 8K + B 16K), aux @48K
    float* auxm = (float*)(lds + 49152);    // [4][128]
    const int t = threadIdx.x;
    const int l = t & 63, w = t >> 6;
    const int g = l >> 4, c = l & 15;
    const int wr = w >> 2, wc = w & 3;      // 2x4 wave grid: 128 rows x 256 cols
    const int bid = blockIdx.x;             // 8192 blocks = 256 bx x 32 by
    const int xcd = bid & 7, idx = bid >> 3;
    const int bx = xcd + 8 * (idx & 31);
    const int by = idx >> 5;
    const int row0 = bx * 128;
    const int col0 = by * 256;

    f32x4 acc[4][4];
    #pragma unroll
    for (int m = 0; m < 4; ++m)
        #pragma unroll
        for (int n = 0; n < 4; ++n) acc[m][n] = (f32x4){0.f, 0.f, 0.f, 0.f};

    const char* xg = (const char*)xbf  + (size_t)row0 * 512;
    const char* cg = (const char*)cbbf + (size_t)col0 * 512;

#define STAGE(buf, ks)                                                         \
    do {                                                                       \
        const int kb_ = (ks) * 64;                                             \
        unsigned char* la_ = lds + (buf) * 24576;                              \
        {   /* A: 128 rows x 4 chunks = 512 = one per thread */                \
            int row_ = t >> 2, pc_ = t & 3;                                    \
            int sz_ = (row_ >> 1) & 3;                                         \
            gl_lds16(xg + (size_t)row_ * 512 + kb_ + ((pc_ ^ sz_) * 16),       \
                     la_ + t * 16);                                            \
        }                                                                      \
        _Pragma("unroll")                                                      \
        for (int r_ = 0; r_ < 2; ++r_) {  /* B: 256 rows x 4 chunks = 1024 */  \
            int i_ = r_ * 512 + t;                                             \
            int row_ = i_ >> 2, pc_ = i_ & 3;                                  \
            int sz_ = (row_ >> 1) & 3;                                         \
            gl_lds16(cg + (size_t)row_ * 512 + kb_ + ((pc_ ^ sz_) * 16),       \
                     la_ + 8192 + i_ * 16);                                    \
        }                                                                      \
    } while (0)

#define COMPUTE(buf)                                                           \
    do {                                                                       \
        const unsigned char* la_ = lds + (buf) * 24576;                        \
        const unsigned char* lb_ = la_ + 8192;                                 \
        const int swq_ = (g ^ ((c >> 1) & 3)) * 16;                            \
        short8v af[4], bv[4];                                                  \
        _Pragma("unroll")                                                      \
        for (int m = 0; m < 4; ++m)                                            \
            af[m] = *(const short8v*)(la_ + (64 * wr + 16 * m + c) * 64 + swq_); \
        _Pragma("unroll")                                                      \
        for (int n = 0; n < 4; ++n)                                            \
            bv[n] = *(const short8v*)(lb_ + (64 * wc + 16 * n + c) * 64 + swq_); \
        __builtin_amdgcn_s_setprio(1);                                         \
        _Pragma("unroll")                                                      \
        for (int m = 0; m < 4; ++m)                                            \
            _Pragma("unroll")                                                  \
            for (int n = 0; n < 4; ++n)                                        \
                acc[m][n] = __builtin_amdgcn_mfma_f32_16x16x32_bf16(           \
                    af[m], bv[n], acc[m][n], 0, 0, 0);                         \
        __builtin_amdgcn_s_setprio(0);                                         \
    } while (0)

    STAGE(0, 0);
    asm volatile("s_waitcnt vmcnt(0)" ::: "memory");
    __syncthreads();

    #pragma unroll
    for (int s = 0; s < 8; ++s) {
        if (s < 7) STAGE((s + 1) & 1, s + 1);          // prefetch next K-step
        COMPUTE(s & 1);
        asm volatile("s_waitcnt vmcnt(0)" ::: "memory");
        __syncthreads();
    }
#undef STAGE
#undef COMPUTE

    // ---- epilogue: C/D layout col = c, row = 4*g + j within each 16x16 ----
    #pragma unroll
    for (int m = 0; m < 4; ++m)
        #pragma unroll
        for (int j = 0; j < 4; ++j) {
            float v = acc[m][0][j];
            #pragma unroll
            for (int n = 1; n < 4; ++n) v = fmaxf(v, acc[m][n][j]);
            #pragma unroll
            for (int msk = 1; msk < 16; msk <<= 1)
                v = fmaxf(v, __shfl_xor(v, msk, 64));
            if (c == 0) auxm[wc * 128 + 64 * wr + 16 * m + 4 * g + j] = v;
        }
    __syncthreads();

    if (t < 128) {
        float vm = fmaxf(fmaxf(auxm[t], auxm[128 + t]),
                         fmaxf(auxm[256 + t], auxm[384 + t]));
        unsigned int ou = atomicMax(&gmax[row0 + t], mono_f32(vm));
        auxm[t] = fmaxf(vm, invmono_f32(ou));
    }
    __syncthreads();

    #pragma unroll
    for (int m = 0; m < 4; ++m)
        #pragma unroll
        for (int j = 0; j < 4; ++j) {
            int lrow = 64 * wr + 16 * m + 4 * g + j;
            float thr = auxm[lrow] - MARGIN;
            #pragma unroll
            for (int n = 0; n < 4; ++n) {
                float s = acc[m][n][j];
                if (s >= thr) {
                    int row = row0 + lrow;
                    unsigned int idx2 = atomicAdd(&ccnt[row], 1u);
                    if (idx2 < CAP)
                        cand[((size_t)row << 6) + idx2] =
                            (unsigned short)(col0 + 64 * wc + 16 * n + c);
                }
            }
        }
}

// ---------------------------------------------------------------------------
// Exact np-chain distance: ascending-k fp32 fmaf chain (BLAS order).
// ---------------------------------------------------------------------------
__device__ __forceinline__ unsigned long long np_dist_pack(
    const float4* __restrict__ xr4, const float* __restrict__ cb,
    int k, float X2, const float* __restrict__ c2)
{
    #pragma clang fp contract(off)
    const float4* cr4 = (const float4*)(cb + (size_t)k * DIM);
    float a = 0.f;
    #pragma unroll 8
    for (int t4 = 0; t4 < DIM / 4; ++t4) {
        float4 xv = xr4[t4];
        float4 cv = cr4[t4];
        a = fmaf(xv.x, cv.x, a);
        a = fmaf(xv.y, cv.y, a);
        a = fmaf(xv.z, cv.z, a);
        a = fmaf(xv.w, cv.w, a);
    }
    float u  = X2 - 2.0f * a;
    float dd = u + c2[k];
    return ((unsigned long long)mono_f32(dd) << 32) | (unsigned int)k;
}

// ---------------------------------------------------------------------------
// Phase 2 FUSED: exact rescore + gather + output + loss partial. One wave
// per row. cnt==1 fast path: superset guarantee means a singleton candidate
// IS the argmin — skip the 256-long dependent FMA chain (wave-uniform branch).
// ---------------------------------------------------------------------------
__global__ __launch_bounds__(256) void select_finalize(
    const float* __restrict__ x, const float* __restrict__ cb,
    const float* __restrict__ x2, const float* __restrict__ c2,
    const unsigned int* __restrict__ ccnt, const unsigned short* __restrict__ cand,
    float* __restrict__ out, float* __restrict__ partial)
{
    __shared__ float wsum[4];
    const int t = threadIdx.x;
    const int l = t & 63, wv = t >> 6;
    const int row = blockIdx.x * 4 + wv;
    const unsigned int cnt = ccnt[row];
    const float4* xr4 = (const float4*)(x + (size_t)row * DIM);
    int id;

    if (cnt == 1) {
        id = (int)cand[(size_t)row << 6];          // singleton = winner
    } else {
        const float X2 = x2[row];
        unsigned long long bp = ~0ull;
        if (cnt <= CAP) {
            if (l < (int)cnt) {
                int k = (int)cand[((size_t)row << 6) + l];
                bp = np_dist_pack(xr4, cb, k, X2, c2);
            }
        } else {
            for (int k = l; k < KCB; k += 64) {
                unsigned long long pk = np_dist_pack(xr4, cb, k, X2, c2);
                if (pk < bp) bp = pk;
            }
        }
        #pragma unroll
        for (int m = 1; m < 64; m <<= 1) {
            unsigned long long v = shfl_xor_u64(bp, m);
            if (v < bp) bp = v;
        }
        id = (int)(bp & 0xFFFFFFFFu);
    }

    // gather + write + loss: lane l handles float4 index l (row = 64 float4s)
    const float4* cp = (const float4*)(cb + (size_t)id * DIM);
    float4*       op = (float4*)(out + (size_t)row * DIM);
    float4 xv = xr4[l], qv = cp[l];
    op[l] = qv;
    float dx = xv.x - qv.x, dy = xv.y - qv.y;
    float dz = xv.z - qv.z, dw = xv.w - qv.w;
    float s = dx * dx + dy * dy + dz * dz + dw * dw;
    #pragma unroll
    for (int m = 1; m < 64; m <<= 1) s += __shfl_xor(s, m, 64);
    if (l == 0) {
        out[(size_t)N_TOK * DIM + row] = (float)id;
        wsum[wv] = s;
    }
    __syncthreads();
    if (t == 0)
        partial[blockIdx.x] = (wsum[0] + wsum[1]) + (wsum[2] + wsum[3]);
}

// ---------------------------------------------------------------------------
// fp32 fallback score kernel (used only if ws is too small)
// ---------------------------------------------------------------------------
__global__ __launch_bounds__(256, 4) void score_argmin(const float* __restrict__ x,
                                                       const float* __restrict__ cb,
                                                       const float* __restrict__ c2,
                                                       const float* __restrict__ x2,
                                                       unsigned long long* __restrict__ best) {
    #pragma clang fp contract(off)
    __shared__ float As[16][128];
    __shared__ float Bs[16][128];
    const int row0 = blockIdx.x * 128;
    const int col0 = blockIdx.y * 128;
    const int t = threadIdx.x;
    const int tn = t & 15, tm = t >> 4;
    const int lrow = t >> 1, lseg = (t & 1) * 4;
    float acc[8][8];
    #pragma unroll
    for (int i = 0; i < 8; ++i)
        #pragma unroll
        for (int j = 0; j < 8; ++j) acc[i][j] = 0.f;
    const float* xp = x  + (size_t)(row0 + lrow) * DIM + lseg;
    const float* cp = cb + (size_t)(col0 + lrow) * DIM + lseg;
    for (int k0 = 0; k0 < DIM; k0 += 16) {
        float4 a0 = *(const float4*)(xp + k0);
        float4 a1 = *(const float4*)(xp + k0 + 8);
        float4 b0 = *(const float4*)(cp + k0);
        float4 b1 = *(const float4*)(cp + k0 + 8);
        __syncthreads();
        As[lseg + 0][lrow] = a0.x; As[lseg + 1][lrow] = a0.y;
        As[lseg + 2][lrow] = a0.z; As[lseg + 3][lrow] = a0.w;
        As[8 + lseg + 0][lrow] = a1.x; As[8 + lseg + 1][lrow] = a1.y;
        As[8 + lseg + 2][lrow] = a1.z; As[8 + lseg + 3][lrow] = a1.w;
        Bs[lseg + 0][lrow] = b0.x; Bs[lseg + 1][lrow] = b0.y;
        Bs[lseg + 2][lrow] = b0.z; Bs[lseg + 3][lrow] = b0.w;
        Bs[8 + lseg + 0][lrow] = b1.x; Bs[8 + lseg + 1][lrow] = b1.y;
        Bs[8 + lseg + 2][lrow] = b1.z; Bs[8 + lseg + 3][lrow] = b1.w;
        __syncthreads();
        #pragma unroll
        for (int kk = 0; kk < 16; ++kk) {
            float a[8], b[8];
            *(float4*)(a)     = *(const float4*)&As[kk][tm * 4];
            *(float4*)(a + 4) = *(const float4*)&As[kk][64 + tm * 4];
            *(float4*)(b)     = *(const float4*)&Bs[kk][tn * 4];
            *(float4*)(b + 4) = *(const float4*)&Bs[kk][64 + tn * 4];
            #pragma unroll
            for (int i = 0; i < 8; ++i)
                #pragma unroll
                for (int j = 0; j < 8; ++j)
                    acc[i][j] = fmaf(a[i], b[j], acc[i][j]);
        }
    }
    float c2v[8], x2v[8];
    #pragma unroll
    for (int j = 0; j < 4; ++j) {
        c2v[j]     = c2[col0 + tn * 4 + j];
        c2v[4 + j] = c2[col0 + 64 + tn * 4 + j];
    }
    #pragma unroll
    for (int i = 0; i < 4; ++i) {
        x2v[i]     = x2[row0 + tm * 4 + i];
        x2v[4 + i] = x2[row0 + 64 + tm * 4 + i];
    }
    #pragma unroll
    for (int i = 0; i < 8; ++i) {
        unsigned long long bp = ~0ull;
        #pragma unroll
        for (int j = 0; j < 8; ++j) {
            float tt = 2.0f * acc[i][j];
            float u  = x2v[i] - tt;
            float dd = u + c2v[j];
            int id = col0 + ((j < 4) ? (tn * 4 + j) : (64 + tn * 4 + (j - 4)));
            unsigned long long pk = ((unsigned long long)mono_f32(dd) << 32) | (unsigned int)id;
            if (pk < bp) bp = pk;
        }
        #pragma unroll
        for (int m = 1; m < 16; m <<= 1) {
            unsigned long long v = shfl_xor_u64(bp, m);
            if (v < bp) bp = v;
        }
        if (tn == 0) {
            int gr = row0 + ((i < 4) ? (tm * 4 + i) : (64 + tm * 4 + (i - 4)));
            atomicMin(&best[gr], bp);
        }
    }
}

// ---------------------------------------------------------------------------
// fallback finalize (16 rows/block) — used only on the fp32 path
// ---------------------------------------------------------------------------
__global__ __launch_bounds__(256) void finalize(const float* __restrict__ x,
                                                const float* __restrict__ cb,
                                                const unsigned long long* __restrict__ best,
                                                float* __restrict__ out,
                                                float* __restrict__ partial) {
    __shared__ float rsum[16];
    const int t = threadIdx.x;
    const int rloc = t >> 4, seg = t & 15;
    const int r = blockIdx.x * 16 + rloc;
    const int id = (int)(best[r] & 0xFFFFFFFFu);
    const float4* xp = (const float4*)(x  + (size_t)r  * DIM) + seg * 4;
    const float4* cp = (const float4*)(cb + (size_t)id * DIM) + seg * 4;
    float4*       op = (float4*)(out + (size_t)r * DIM) + seg * 4;
    float s = 0.f;
    #pragma unroll
    for (int i = 0; i < 4; ++i) {
        float4 xv = xp[i], qv = cp[i];
        op[i] = qv;
        float dx = xv.x - qv.x, dy = xv.y - qv.y;
        float dz = xv.z - qv.z, dw = xv.w - qv.w;
        s += dx * dx + dy * dy + dz * dz + dw * dw;
    }
    #pragma unroll
    for (int m = 1; m < 16; m <<= 1) s += __shfl_xor(s, m, 64);
    if (seg == 0) {
        rsum[rloc] = s;
        out[(size_t)N_TOK * DIM + r] = (float)id;
    }
    __syncthreads();
    if (t == 0) {
        float bs = 0.f;
        #pragma unroll
        for (int i = 0; i < 16; ++i) bs += rsum[i];
        partial[blockIdx.x] = bs;
    }
}

// single block: sum n partials, write loss scalar
__global__ __launch_bounds__(256) void reduce_loss(const float* __restrict__ partial,
                                                   int n, float* __restrict__ out) {
    float s = 0.f;
    for (int i = threadIdx.x; i < n / 4; i += 256) {
        float4 v = ((const float4*)partial)[i];
        s += (v.x + v.y) + (v.z + v.w);
    }
    #pragma unroll
    for (int o = 32; o > 0; o >>= 1) s += __shfl_down(s, o, 64);
    __shared__ float w4[4];
    if ((threadIdx.x & 63) == 0) w4[threadIdx.x >> 6] = s;
    __syncthreads();
    if (threadIdx.x == 0)
        out[(size_t)N_TOK * DIM + N_TOK] =
            (w4[0] + w4[1] + w4[2] + w4[3]) * (1.25f / ((float)N_TOK * (float)DIM));
}

// ---------------------------------------------------------------------------
extern "C" void kernel_launch(void* const* d_in, const int* in_sizes, int n_in,
                              void* d_out, int out_size, void* d_ws, size_t ws_size,
                              hipStream_t stream) {
    const float* x     = (const float*)d_in[0];
    const float* emb   = (const float*)d_in[1];
    const float* w_out = (const float*)d_in[2];
    float* out = (float*)d_out;

    char* ws = (char*)d_ws;
    unsigned long long* best = (unsigned long long*)ws;              //        0 (256 KiB, fallback only)
    float* x2 = (float*)(ws + 262400);                               //   262400
    float* wT = (float*)(ws + 393472);                               //   393472 (reused as loss partial)
    float* cb = (float*)(ws + 655616);                               //   655616 (8 MiB)
    float* c2 = (float*)(ws + 9044224);                              //  9044224
    unsigned int*   gmax = (unsigned int*)(ws + 9076992);            //  9076992 (128 KiB)
    unsigned int*   ccnt = (unsigned int*)(ws + 9208064);            //  9208064 (128 KiB)
    unsigned short* cand = (unsigned short*)(ws + 9339136);          //  9339136 (4 MiB)
    unsigned short* xbf  = (unsigned short*)(ws + 13533440);         // 13533440 (16 MiB)
    unsigned short* cbbf = (unsigned short*)(ws + 30310656);         // 30310656 (4 MiB)
    float* partial = wT;                                             // 32 KiB, reuse
    const size_t NEED = 34504960;
    const bool useMfma = (ws_size >= NEED);

    if (useMfma) {
        hipMemsetAsync(gmax, 0, 262144, stream);   // gmax + ccnt contiguous
        fused_pre     <<<64 + N_TOK * 2 / 256, 256, 0, stream>>>(w_out, wT, x, x2, (uint4*)xbf);
        build_codebook<<<KCB / KPB, 256, 0, stream>>>(emb, wT, cb, c2, cbbf);
        score_collect <<<8192, 512, 0, stream>>>(xbf, cbbf, gmax, ccnt, cand);
        select_finalize<<<N_TOK / 4, 256, 0, stream>>>(x, cb, x2, c2, ccnt, cand, out, partial);
        reduce_loss   <<<1, 256, 0, stream>>>(partial, N_TOK / 4, out);
    } else {
        hipMemsetAsync(best, 0xFF, 262144, stream);
        fused_pre     <<<64 + N_TOK * 2 / 256, 256, 0, stream>>>(w_out, wT, x, x2, (uint4*)xbf);
        build_codebook<<<KCB / KPB, 256, 0, stream>>>(emb, wT, cb, c2, (unsigned short*)0);
        score_argmin  <<<dim3(N_TOK / 128, KCB / 128), 256, 0, stream>>>(x, cb, c2, x2, best);
        finalize      <<<N_TOK / 16, 256, 0, stream>>>(x, cb, best, out, partial);
        reduce_loss   <<<1, 256, 0, stream>>>(partial, N_TOK / 16, out);
    }
}

// Round 19
// 428.287 us; speedup vs baseline: 1.2415x; 1.0065x over previous
//
#include <hip/hip_runtime.h>
#include <hip/hip_bf16.h>

#define N_TOK 32768
#define DIM   256
#define KCB   8192
#define CAP   64
#define MARGIN 1.75e-4f

typedef __attribute__((ext_vector_type(8))) short short8v;   // 8 bf16
typedef __attribute__((ext_vector_type(4))) float f32x4;

__device__ __forceinline__ unsigned int mono_f32(float f) {
    unsigned int u = __float_as_uint(f);
    return (u >> 31) ? ~u : (u | 0x80000000u);
}
__device__ __forceinline__ float invmono_f32(unsigned int m) {
    unsigned int u = (m & 0x80000000u) ? (m & 0x7FFFFFFFu) : ~m;
    return __uint_as_float(u);
}
__device__ __forceinline__ unsigned long long shfl_xor_u64(unsigned long long v, int m) {
    unsigned int lo = (unsigned int)v, hi = (unsigned int)(v >> 32);
    lo = __shfl_xor(lo, m, 64);
    hi = __shfl_xor(hi, m, 64);
    return ((unsigned long long)hi << 32) | lo;
}
__device__ __forceinline__ void gl_lds16(const void* g, void* l) {
    __builtin_amdgcn_global_load_lds(
        (const __attribute__((address_space(1))) unsigned int*)g,
        (__attribute__((address_space(3))) unsigned int*)l, 16, 0, 0);
}
__device__ __forceinline__ unsigned int rne16(float f) {
    unsigned int b = __float_as_uint(f);
    return (b + 0x7FFFu + ((b >> 16) & 1u)) >> 16;
}

// ---------------------------------------------------------------------------
// pre_all: ONE kernel for the whole front-end.
//   blocks 0..1023:  codebook — cb[k][d] = sum_j emb[k][j]*w_out[d][j]
//                    (sequential-j fp32 FMA chain == BLAS order; w_out read
//                    DIRECTLY row-major — 256 KB, L2-hot, values identical so
//                    bit-exactness preserved) + bf16 cast + c2 in exact
//                    numpy pairwise order (squares staged in LDS).
//   blocks 1024..1279: x sumsq (exact np pairwise) + fp32->bf16 cast.
// The two halves are independent and overlap inside one dispatch.
// ---------------------------------------------------------------------------
#define KPB 8
__global__ __launch_bounds__(256) void pre_all(const float* __restrict__ emb,
                                               const float* __restrict__ w_out,
                                               float* __restrict__ cb,
                                               float* __restrict__ c2,
                                               unsigned short* __restrict__ cbbf,
                                               const float* __restrict__ x,
                                               float* __restrict__ x2,
                                               uint4* __restrict__ xbf) {
    #pragma clang fp contract(off)
    __shared__ float e[KPB][DIM];
    const int t = threadIdx.x;

    if (blockIdx.x < KCB / KPB) {
        // ---- codebook half ----
        const int k0 = blockIdx.x * KPB;
        for (int i = t; i < KPB * DIM / 4; i += 256)
            ((float4*)&e[0][0])[i] = ((const float4*)(emb + (size_t)k0 * DIM))[i];
        __syncthreads();
        const int d = t;
        float acc[KPB];
        #pragma unroll
        for (int kk = 0; kk < KPB; ++kk) acc[kk] = 0.f;
        const float* wrow = w_out + (size_t)d * DIM;
        for (int j = 0; j < DIM; ++j) {          // ascending j: BLAS FMA chain
            float w = wrow[j];                   // L2-hot (w_out = 256 KB)
            #pragma unroll
            for (int kk = 0; kk < KPB; ++kk)
                acc[kk] = fmaf(e[kk][j], w, acc[kk]);
        }
        __syncthreads();                         // done reading e
        #pragma unroll
        for (int kk = 0; kk < KPB; ++kk) {
            cb[(size_t)(k0 + kk) * DIM + d] = acc[kk];
            if (cbbf)
                cbbf[(size_t)(k0 + kk) * DIM + d] = (unsigned short)rne16(acc[kk]);
            e[kk][d] = acc[kk] * acc[kk];        // fl(cb^2) = numpy's a*a temp
        }
        __syncthreads();
        if (t < 16) {                            // np pairwise: 8-acc + tree
            const int kk = t >> 1, h = t & 1;
            const float* b = &e[kk][h * 128];
            float r0 = 0.f, r1 = 0.f, r2 = 0.f, r3 = 0.f,
                  r4 = 0.f, r5 = 0.f, r6 = 0.f, r7 = 0.f;
            #pragma unroll
            for (int i = 0; i < 128; i += 8) {
                r0 = r0 + b[i + 0]; r1 = r1 + b[i + 1];
                r2 = r2 + b[i + 2]; r3 = r3 + b[i + 3];
                r4 = r4 + b[i + 4]; r5 = r5 + b[i + 5];
                r6 = r6 + b[i + 6]; r7 = r7 + b[i + 7];
            }
            float half = ((r0 + r1) + (r2 + r3)) + ((r4 + r5) + (r6 + r7));
            float other = __shfl_xor(half, 1, 64);
            if (h == 0) c2[k0 + kk] = half + other;
        }
        return;
    }

    // ---- x half: sumsq (np order) + bf16 cast ----
    int idx = (blockIdx.x - KCB / KPB) * 256 + t;
    int r = idx >> 1, h = idx & 1;
    const float* b = x + (size_t)r * DIM + h * 128;
    uint4* dst = xbf + ((size_t)r * 32 + h * 16);
    float r0 = 0.f, r1 = 0.f, r2 = 0.f, r3 = 0.f,
          r4 = 0.f, r5 = 0.f, r6 = 0.f, r7 = 0.f;
    #pragma unroll
    for (int i = 0; i < 128; i += 8) {
        float4 p = *(const float4*)(b + i);
        float4 q = *(const float4*)(b + i + 4);
        uint4 u;
        u.x = rne16(p.x) | (rne16(p.y) << 16);
        u.y = rne16(p.z) | (rne16(p.w) << 16);
        u.z = rne16(q.x) | (rne16(q.y) << 16);
        u.w = rne16(q.z) | (rne16(q.w) << 16);
        dst[i >> 3] = u;
        r0 = r0 + p.x * p.x; r1 = r1 + p.y * p.y;
        r2 = r2 + p.z * p.z; r3 = r3 + p.w * p.w;
        r4 = r4 + q.x * q.x; r5 = r5 + q.y * q.y;
        r6 = r6 + q.z * q.z; r7 = r7 + q.w * q.w;
    }
    float half = ((r0 + r1) + (r2 + r3)) + ((r4 + r5) + (r6 + r7));
    float other = __shfl_xor(half, 1, 64);
    if (h == 0) x2[r] = half + other;
}

// ---------------------------------------------------------------------------
// Phase 1: bf16 MFMA score GEMM + per-row running max + candidate collection.
// Proven structure: 128x256 tile, 8 waves 2x4, 64x64/wave, 2 blocks/CU,
// BK=32 dbuf + prefetch, conflict-free swizzle, s_setprio around MFMA.
// ---------------------------------------------------------------------------
__global__ __launch_bounds__(512, 4) void score_collect(
    const unsigned short* __restrict__ xbf,
    const unsigned short* __restrict__ cbbf,
    unsigned int* __restrict__ gmax,
    unsigned int* __restrict__ ccnt,
    unsigned short* __restrict__ cand)
{
    __shared__ unsigned char lds[51200];    // buf0 @0, buf1 @24K (A 8K + B 16K), aux @48K
    float* auxm = (float*)(lds + 49152);    // [4][128]
    const int t = threadIdx.x;
    const int l = t & 63, w = t >> 6;
    const int g = l >> 4, c = l & 15;
    const int wr = w >> 2, wc = w & 3;      // 2x4 wave grid: 128 rows x 256 cols
    const int bid = blockIdx.x;             // 8192 blocks = 256 bx x 32 by
    const int xcd = bid & 7, idx = bid >> 3;
    const int bx = xcd + 8 * (idx & 31);
    const int by = idx >> 5;
    const int row0 = bx * 128;
    const int col0 = by * 256;

    f32x4 acc[4][4];
    #pragma unroll
    for (int m = 0; m < 4; ++m)
        #pragma unroll
        for (int n = 0; n < 4; ++n) acc[m][n] = (f32x4){0.f, 0.f, 0.f, 0.f};

    const char* xg = (const char*)xbf  + (size_t)row0 * 512;
    const char* cg = (const char*)cbbf + (size_t)col0 * 512;

#define STAGE(buf, ks)                                                         \
    do {                                                                       \
        const int kb_ = (ks) * 64;                                             \
        unsigned char* la_ = lds + (buf) * 24576;                              \
        {   /* A: 128 rows x 4 chunks = 512 = one per thread */                \
            int row_ = t >> 2, pc_ = t & 3;                                    \
            int sz_ = (row_ >> 1) & 3;                                         \
            gl_lds16(xg + (size_t)row_ * 512 + kb_ + ((pc_ ^ sz_) * 16),       \
                     la_ + t * 16);                                            \
        }                                                                      \
        _Pragma("unroll")                                                      \
        for (int r_ = 0; r_ < 2; ++r_) {  /* B: 256 rows x 4 chunks = 1024 */  \
            int i_ = r_ * 512 + t;                                             \
            int row_ = i_ >> 2, pc_ = i_ & 3;                                  \
            int sz_ = (row_ >> 1) & 3;                                         \
            gl_lds16(cg + (size_t)row_ * 512 + kb_ + ((pc_ ^ sz_) * 16),       \
                     la_ + 8192 + i_ * 16);                                    \
        }                                                                      \
    } while (0)

#define COMPUTE(buf)                                                           \
    do {                                                                       \
        const unsigned char* la_ = lds + (buf) * 24576;                        \
        const unsigned char* lb_ = la_ + 8192;                                 \
        const int swq_ = (g ^ ((c >> 1) & 3)) * 16;                            \
        short8v af[4], bv[4];                                                  \
        _Pragma("unroll")                                                      \
        for (int m = 0; m < 4; ++m)                                            \
            af[m] = *(const short8v*)(la_ + (64 * wr + 16 * m + c) * 64 + swq_); \
        _Pragma("unroll")                                                      \
        for (int n = 0; n < 4; ++n)                                            \
            bv[n] = *(const short8v*)(lb_ + (64 * wc + 16 * n + c) * 64 + swq_); \
        __builtin_amdgcn_s_setprio(1);                                         \
        _Pragma("unroll")                                                      \
        for (int m = 0; m < 4; ++m)                                            \
            _Pragma("unroll")                                                  \
            for (int n = 0; n < 4; ++n)                                        \
                acc[m][n] = __builtin_amdgcn_mfma_f32_16x16x32_bf16(           \
                    af[m], bv[n], acc[m][n], 0, 0, 0);                         \
        __builtin_amdgcn_s_setprio(0);                                         \
    } while (0)

    STAGE(0, 0);
    asm volatile("s_waitcnt vmcnt(0)" ::: "memory");
    __syncthreads();

    #pragma unroll
    for (int s = 0; s < 8; ++s) {
        if (s < 7) STAGE((s + 1) & 1, s + 1);          // prefetch next K-step
        COMPUTE(s & 1);
        asm volatile("s_waitcnt vmcnt(0)" ::: "memory");
        __syncthreads();
    }
#undef STAGE
#undef COMPUTE

    // ---- epilogue: C/D layout col = c, row = 4*g + j within each 16x16 ----
    #pragma unroll
    for (int m = 0; m < 4; ++m)
        #pragma unroll
        for (int j = 0; j < 4; ++j) {
            float v = acc[m][0][j];
            #pragma unroll
            for (int n = 1; n < 4; ++n) v = fmaxf(v, acc[m][n][j]);
            #pragma unroll
            for (int msk = 1; msk < 16; msk <<= 1)
                v = fmaxf(v, __shfl_xor(v, msk, 64));
            if (c == 0) auxm[wc * 128 + 64 * wr + 16 * m + 4 * g + j] = v;
        }
    __syncthreads();

    if (t < 128) {
        float vm = fmaxf(fmaxf(auxm[t], auxm[128 + t]),
                         fmaxf(auxm[256 + t], auxm[384 + t]));
        unsigned int ou = atomicMax(&gmax[row0 + t], mono_f32(vm));
        auxm[t] = fmaxf(vm, invmono_f32(ou));
    }
    __syncthreads();

    #pragma unroll
    for (int m = 0; m < 4; ++m)
        #pragma unroll
        for (int j = 0; j < 4; ++j) {
            int lrow = 64 * wr + 16 * m + 4 * g + j;
            float thr = auxm[lrow] - MARGIN;
            #pragma unroll
            for (int n = 0; n < 4; ++n) {
                float s = acc[m][n][j];
                if (s >= thr) {
                    int row = row0 + lrow;
                    unsigned int idx2 = atomicAdd(&ccnt[row], 1u);
                    if (idx2 < CAP)
                        cand[((size_t)row << 6) + idx2] =
                            (unsigned short)(col0 + 64 * wc + 16 * n + c);
                }
            }
        }
}

// ---------------------------------------------------------------------------
// Exact np-chain distance: ascending-k fp32 fmaf chain (BLAS order).
// ---------------------------------------------------------------------------
__device__ __forceinline__ unsigned long long np_dist_pack(
    const float4* __restrict__ xr4, const float* __restrict__ cb,
    int k, float X2, const float* __restrict__ c2)
{
    #pragma clang fp contract(off)
    const float4* cr4 = (const float4*)(cb + (size_t)k * DIM);
    float a = 0.f;
    #pragma unroll 8
    for (int t4 = 0; t4 < DIM / 4; ++t4) {
        float4 xv = xr4[t4];
        float4 cv = cr4[t4];
        a = fmaf(xv.x, cv.x, a);
        a = fmaf(xv.y, cv.y, a);
        a = fmaf(xv.z, cv.z, a);
        a = fmaf(xv.w, cv.w, a);
    }
    float u  = X2 - 2.0f * a;
    float dd = u + c2[k];
    return ((unsigned long long)mono_f32(dd) << 32) | (unsigned int)k;
}

// ---------------------------------------------------------------------------
// Phase 2 FUSED: exact rescore + gather + output + loss partial. One wave
// per row; cnt==1 fast path (superset guarantee => singleton is the winner).
// ---------------------------------------------------------------------------
__global__ __launch_bounds__(256) void select_finalize(
    const float* __restrict__ x, const float* __restrict__ cb,
    const float* __restrict__ x2, const float* __restrict__ c2,
    const unsigned int* __restrict__ ccnt, const unsigned short* __restrict__ cand,
    float* __restrict__ out, float* __restrict__ partial)
{
    __shared__ float wsum[4];
    const int t = threadIdx.x;
    const int l = t & 63, wv = t >> 6;
    const int row = blockIdx.x * 4 + wv;
    const unsigned int cnt = ccnt[row];
    const float4* xr4 = (const float4*)(x + (size_t)row * DIM);
    int id;

    if (cnt == 1) {
        id = (int)cand[(size_t)row << 6];
    } else {
        const float X2 = x2[row];
        unsigned long long bp = ~0ull;
        if (cnt <= CAP) {
            if (l < (int)cnt) {
                int k = (int)cand[((size_t)row << 6) + l];
                bp = np_dist_pack(xr4, cb, k, X2, c2);
            }
        } else {
            for (int k = l; k < KCB; k += 64) {
                unsigned long long pk = np_dist_pack(xr4, cb, k, X2, c2);
                if (pk < bp) bp = pk;
            }
        }
        #pragma unroll
        for (int m = 1; m < 64; m <<= 1) {
            unsigned long long v = shfl_xor_u64(bp, m);
            if (v < bp) bp = v;
        }
        id = (int)(bp & 0xFFFFFFFFu);
    }

    const float4* cp = (const float4*)(cb + (size_t)id * DIM);
    float4*       op = (float4*)(out + (size_t)row * DIM);
    float4 xv = xr4[l], qv = cp[l];
    op[l] = qv;
    float dx = xv.x - qv.x, dy = xv.y - qv.y;
    float dz = xv.z - qv.z, dw = xv.w - qv.w;
    float s = dx * dx + dy * dy + dz * dz + dw * dw;
    #pragma unroll
    for (int m = 1; m < 64; m <<= 1) s += __shfl_xor(s, m, 64);
    if (l == 0) {
        out[(size_t)N_TOK * DIM + row] = (float)id;
        wsum[wv] = s;
    }
    __syncthreads();
    if (t == 0)
        partial[blockIdx.x] = (wsum[0] + wsum[1]) + (wsum[2] + wsum[3]);
}

// ---------------------------------------------------------------------------
// fp32 fallback score kernel (used only if ws is too small)
// ---------------------------------------------------------------------------
__global__ __launch_bounds__(256, 4) void score_argmin(const float* __restrict__ x,
                                                       const float* __restrict__ cb,
                                                       const float* __restrict__ c2,
                                                       const float* __restrict__ x2,
                                                       unsigned long long* __restrict__ best) {
    #pragma clang fp contract(off)
    __shared__ float As[16][128];
    __shared__ float Bs[16][128];
    const int row0 = blockIdx.x * 128;
    const int col0 = blockIdx.y * 128;
    const int t = threadIdx.x;
    const int tn = t & 15, tm = t >> 4;
    const int lrow = t >> 1, lseg = (t & 1) * 4;
    float acc[8][8];
    #pragma unroll
    for (int i = 0; i < 8; ++i)
        #pragma unroll
        for (int j = 0; j < 8; ++j) acc[i][j] = 0.f;
    const float* xp = x  + (size_t)(row0 + lrow) * DIM + lseg;
    const float* cp = cb + (size_t)(col0 + lrow) * DIM + lseg;
    for (int k0 = 0; k0 < DIM; k0 += 16) {
        float4 a0 = *(const float4*)(xp + k0);
        float4 a1 = *(const float4*)(xp + k0 + 8);
        float4 b0 = *(const float4*)(cp + k0);
        float4 b1 = *(const float4*)(cp + k0 + 8);
        __syncthreads();
        As[lseg + 0][lrow] = a0.x; As[lseg + 1][lrow] = a0.y;
        As[lseg + 2][lrow] = a0.z; As[lseg + 3][lrow] = a0.w;
        As[8 + lseg + 0][lrow] = a1.x; As[8 + lseg + 1][lrow] = a1.y;
        As[8 + lseg + 2][lrow] = a1.z; As[8 + lseg + 3][lrow] = a1.w;
        Bs[lseg + 0][lrow] = b0.x; Bs[lseg + 1][lrow] = b0.y;
        Bs[lseg + 2][lrow] = b0.z; Bs[lseg + 3][lrow] = b0.w;
        Bs[8 + lseg + 0][lrow] = b1.x; Bs[8 + lseg + 1][lrow] = b1.y;
        Bs[8 + lseg + 2][lrow] = b1.z; Bs[8 + lseg + 3][lrow] = b1.w;
        __syncthreads();
        #pragma unroll
        for (int kk = 0; kk < 16; ++kk) {
            float a[8], b[8];
            *(float4*)(a)     = *(const float4*)&As[kk][tm * 4];
            *(float4*)(a + 4) = *(const float4*)&As[kk][64 + tm * 4];
            *(float4*)(b)     = *(const float4*)&Bs[kk][tn * 4];
            *(float4*)(b + 4) = *(const float4*)&Bs[kk][64 + tn * 4];
            #pragma unroll
            for (int i = 0; i < 8; ++i)
                #pragma unroll
                for (int j = 0; j < 8; ++j)
                    acc[i][j] = fmaf(a[i], b[j], acc[i][j]);
        }
    }
    float c2v[8], x2v[8];
    #pragma unroll
    for (int j = 0; j < 4; ++j) {
        c2v[j]     = c2[col0 + tn * 4 + j];
        c2v[4 + j] = c2[col0 + 64 + tn * 4 + j];
    }
    #pragma unroll
    for (int i = 0; i < 4; ++i) {
        x2v[i]     = x2[row0 + tm * 4 + i];
        x2v[4 + i] = x2[row0 + 64 + tm * 4 + i];
    }
    #pragma unroll
    for (int i = 0; i < 8; ++i) {
        unsigned long long bp = ~0ull;
        #pragma unroll
        for (int j = 0; j < 8; ++j) {
            float tt = 2.0f * acc[i][j];
            float u  = x2v[i] - tt;
            float dd = u + c2v[j];
            int id = col0 + ((j < 4) ? (tn * 4 + j) : (64 + tn * 4 + (j - 4)));
            unsigned long long pk = ((unsigned long long)mono_f32(dd) << 32) | (unsigned int)id;
            if (pk < bp) bp = pk;
        }
        #pragma unroll
        for (int m = 1; m < 16; m <<= 1) {
            unsigned long long v = shfl_xor_u64(bp, m);
            if (v < bp) bp = v;
        }
        if (tn == 0) {
            int gr = row0 + ((i < 4) ? (tm * 4 + i) : (64 + tm * 4 + (i - 4)));
            atomicMin(&best[gr], bp);
        }
    }
}

// ---------------------------------------------------------------------------
// fallback finalize (16 rows/block) — used only on the fp32 path
// ---------------------------------------------------------------------------
__global__ __launch_bounds__(256) void finalize(const float* __restrict__ x,
                                                const float* __restrict__ cb,
                                                const unsigned long long* __restrict__ best,
                                                float* __restrict__ out,
                                                float* __restrict__ partial) {
    __shared__ float rsum[16];
    const int t = threadIdx.x;
    const int rloc = t >> 4, seg = t & 15;
    const int r = blockIdx.x * 16 + rloc;
    const int id = (int)(best[r] & 0xFFFFFFFFu);
    const float4* xp = (const float4*)(x  + (size_t)r  * DIM) + seg * 4;
    const float4* cp = (const float4*)(cb + (size_t)id * DIM) + seg * 4;
    float4*       op = (float4*)(out + (size_t)r * DIM) + seg * 4;
    float s = 0.f;
    #pragma unroll
    for (int i = 0; i < 4; ++i) {
        float4 xv = xp[i], qv = cp[i];
        op[i] = qv;
        float dx = xv.x - qv.x, dy = xv.y - qv.y;
        float dz = xv.z - qv.z, dw = xv.w - qv.w;
        s += dx * dx + dy * dy + dz * dz + dw * dw;
    }
    #pragma unroll
    for (int m = 1; m < 16; m <<= 1) s += __shfl_xor(s, m, 64);
    if (seg == 0) {
        rsum[rloc] = s;
        out[(size_t)N_TOK * DIM + r] = (float)id;
    }
    __syncthreads();
    if (t == 0) {
        float bs = 0.f;
        #pragma unroll
        for (int i = 0; i < 16; ++i) bs += rsum[i];
        partial[blockIdx.x] = bs;
    }
}

// single block: sum n partials, write loss scalar
__global__ __launch_bounds__(256) void reduce_loss(const float* __restrict__ partial,
                                                   int n, float* __restrict__ out) {
    float s = 0.f;
    for (int i = threadIdx.x; i < n / 4; i += 256) {
        float4 v = ((const float4*)partial)[i];
        s += (v.x + v.y) + (v.z + v.w);
    }
    #pragma unroll
    for (int o = 32; o > 0; o >>= 1) s += __shfl_down(s, o, 64);
    __shared__ float w4[4];
    if ((threadIdx.x & 63) == 0) w4[threadIdx.x >> 6] = s;
    __syncthreads();
    if (threadIdx.x == 0)
        out[(size_t)N_TOK * DIM + N_TOK] =
            (w4[0] + w4[1] + w4[2] + w4[3]) * (1.25f / ((float)N_TOK * (float)DIM));
}

// ---------------------------------------------------------------------------
extern "C" void kernel_launch(void* const* d_in, const int* in_sizes, int n_in,
                              void* d_out, int out_size, void* d_ws, size_t ws_size,
                              hipStream_t stream) {
    const float* x     = (const float*)d_in[0];
    const float* emb   = (const float*)d_in[1];
    const float* w_out = (const float*)d_in[2];
    float* out = (float*)d_out;

    char* ws = (char*)d_ws;
    unsigned long long* best = (unsigned long long*)ws;              //        0 (256 KiB, fallback only)
    float* x2 = (float*)(ws + 262400);                               //   262400
    float* partial = (float*)(ws + 393472);                          //   393472 (32 KiB)
    float* cb = (float*)(ws + 655616);                               //   655616 (8 MiB)
    float* c2 = (float*)(ws + 9044224);                              //  9044224
    unsigned int*   gmax = (unsigned int*)(ws + 9076992);            //  9076992 (128 KiB)
    unsigned int*   ccnt = (unsigned int*)(ws + 9208064);            //  9208064 (128 KiB)
    unsigned short* cand = (unsigned short*)(ws + 9339136);          //  9339136 (4 MiB)
    unsigned short* xbf  = (unsigned short*)(ws + 13533440);         // 13533440 (16 MiB)
    unsigned short* cbbf = (unsigned short*)(ws + 30310656);         // 30310656 (4 MiB)
    const size_t NEED = 34504960;
    const bool useMfma = (ws_size >= NEED);

    const int PRE_GRID = KCB / KPB + N_TOK * 2 / 256;   // 1024 + 256

    if (useMfma) {
        hipMemsetAsync(gmax, 0, 262144, stream);   // gmax + ccnt contiguous
        pre_all       <<<PRE_GRID, 256, 0, stream>>>(emb, w_out, cb, c2, cbbf,
                                                     x, x2, (uint4*)xbf);
        score_collect <<<8192, 512, 0, stream>>>(xbf, cbbf, gmax, ccnt, cand);
        select_finalize<<<N_TOK / 4, 256, 0, stream>>>(x, cb, x2, c2, ccnt, cand, out, partial);
        reduce_loss   <<<1, 256, 0, stream>>>(partial, N_TOK / 4, out);
    } else {
        hipMemsetAsync(best, 0xFF, 262144, stream);
        pre_all       <<<PRE_GRID, 256, 0, stream>>>(emb, w_out, cb, c2,
                                                     (unsigned short*)0, x, x2, (uint4*)xbf);
        score_argmin  <<<dim3(N_TOK / 128, KCB / 128), 256, 0, stream>>>(x, cb, c2, x2, best);
        finalize      <<<N_TOK / 16, 256, 0, stream>>>(x, cb, best, out, partial);
        reduce_loss   <<<1, 256, 0, stream>>>(partial, N_TOK / 16, out);
    }
}